// Round 1
// baseline (3293.286 us; speedup 1.0000x reference)
//
#include <hip/hip_runtime.h>
#include <math.h>

namespace {

constexpr int NQn = 100000, NAn = 200000, NKn = 200000;
constexpr int EPc = 100000, ENc = 100000;

// workspace layout (float element offsets)
constexpr long XS_OFF    = 0;            // 32,000,000 (xs: q,a,k concatenated, 64 per node)
constexpr long Q_OFF     = 32000000;     // 32,000,000
constexpr long OUT_OFF   = 64000000;     // 32,000,000 (attention accum)
constexpr long KREL_OFF  = 96000000;     // 12,800,000 (per-relation reuse)
constexpr long VREL_OFF  = 108800000;    // 12,800,000
constexpr long ALPHA_OFF = 121600000;    //  1,600,000 (per-relation reuse)
constexpr long SMAX_OFF  = 123200000;    //  1,200,000 (uint-encoded, all 4 relations)
constexpr long SSUM_OFF  = 124400000;    //  1,200,000
constexpr long WF_OFF    = 125600000;    //  8*4160 fused rel weights (W 64x64 + b 64)
// total ~125.64M floats = 503 MB

__device__ inline unsigned enc_f(float f) {
    unsigned b = __float_as_uint(f);
    return (b & 0x80000000u) ? ~b : (b | 0x80000000u);
}
__device__ inline float dec_f(unsigned u) {
    return (u & 0x80000000u) ? __uint_as_float(u ^ 0x80000000u) : __uint_as_float(~u);
}
__device__ inline float gelu_f(float x) {
    return 0.5f * x * (1.0f + erff(x * 0.7071067811865475f));
}

// ---- fused relation weights: W'[d][h*32+e] = sum_c w[d][h*32+c]*rel[h][c][e]; b' likewise
__global__ void fuse_weights(const float* __restrict__ kw, const float* __restrict__ kb,
                             const float* __restrict__ vw, const float* __restrict__ vb,
                             const float* __restrict__ a_rel, const float* __restrict__ m_rel,
                             float* __restrict__ wf)
{
    const int r = blockIdx.x >> 1, which = blockIdx.x & 1;
    const int st_tab[4] = {2, 0, 0, 1};
    const int st = st_tab[r];
    const float* w   = (which ? vw : kw) + st * 64 * 64;
    const float* b   = (which ? vb : kb) + st * 64;
    const float* rel = (which ? m_rel : a_rel) + r * 2 * 32 * 32;
    float* out = wf + (long)blockIdx.x * 4160;
    const int tid = threadIdx.x;
    for (int idx = tid; idx < 4096; idx += 256) {
        int d = idx >> 6, col = idx & 63;
        int h = col >> 5, e = col & 31;
        float s = 0.f;
        #pragma unroll
        for (int c = 0; c < 32; ++c) s += w[d * 64 + h * 32 + c] * rel[h * 1024 + c * 32 + e];
        out[idx] = s;
    }
    if (tid < 64) {
        int h = tid >> 5, e = tid & 31;
        float s = 0.f;
        #pragma unroll
        for (int c = 0; c < 32; ++c) s += b[h * 32 + c] * rel[h * 1024 + c * 32 + e];
        out[4096 + tid] = s;
    }
}

// ---- generic per-node GEMM: Y = act_out( act_in(X) @ W + b ), optional skip-mix
// block = 256 threads, 64 nodes/block, thread = 4 nodes x 4 outs
template<int K, bool IN_GELU, bool OUT_RELU, bool MIX>
__global__ void __launch_bounds__(256)
node_gemm(const float* __restrict__ X, const float* __restrict__ W,
          const float* __restrict__ bias, float* __restrict__ Y, int n,
          const float* __restrict__ res, const float* __restrict__ skipv)
{
    __shared__ float ldsW[K * 64];
    __shared__ float ldsX[K * 64];   // [c][node] with XOR-swizzle on node to kill bank conflicts
    const int tid = threadIdx.x;
    const int n0 = blockIdx.x * 64;

    for (int idx = tid; idx < K * 64; idx += 256) ldsW[idx] = W[idx];
    for (int idx = tid; idx < K * 64; idx += 256) {
        int r = idx / K, c = idx - r * K;     // consecutive tid -> consecutive c (coalesced)
        int node = n0 + r; if (node > n - 1) node = n - 1;
        float v = X[(long)node * K + c];
        if (IN_GELU) v = gelu_f(v);
        ldsX[c * 64 + (r ^ (c & 31))] = v;
    }
    __syncthreads();

    const int j = tid & 15;   // output group: cols j*4..j*4+3
    const int i = tid >> 4;   // node group:  rows i*4..i*4+3
    float acc[4][4] = {};
    #pragma unroll 4
    for (int d = 0; d < K; ++d) {
        float4 wv = *(const float4*)&ldsW[d * 64 + j * 4];
        float xv[4];
        #pragma unroll
        for (int k = 0; k < 4; ++k) xv[k] = ldsX[d * 64 + ((i * 4 + k) ^ (d & 31))];
        #pragma unroll
        for (int k = 0; k < 4; ++k) {
            acc[k][0] += xv[k] * wv.x; acc[k][1] += xv[k] * wv.y;
            acc[k][2] += xv[k] * wv.z; acc[k][3] += xv[k] * wv.w;
        }
    }

    const float4 bv = *(const float4*)&bias[j * 4];
    float beta = 0.f;
    if (MIX) beta = 1.f / (1.f + expf(-skipv[0]));
    #pragma unroll
    for (int k = 0; k < 4; ++k) {
        int node = n0 + i * 4 + k;
        if (node < n) {
            float4 o;
            o.x = acc[k][0] + bv.x; o.y = acc[k][1] + bv.y;
            o.z = acc[k][2] + bv.z; o.w = acc[k][3] + bv.w;
            if (OUT_RELU) {
                o.x = fmaxf(o.x, 0.f); o.y = fmaxf(o.y, 0.f);
                o.z = fmaxf(o.z, 0.f); o.w = fmaxf(o.w, 0.f);
            }
            if (MIX) {
                float4 rv = *(const float4*)&res[(long)node * 64 + j * 4];
                o.x = beta * o.x + (1.f - beta) * rv.x;
                o.y = beta * o.y + (1.f - beta) * rv.y;
                o.z = beta * o.z + (1.f - beta) * rv.z;
                o.w = beta * o.w + (1.f - beta) * rv.w;
            }
            *(float4*)&Y[(long)node * 64 + j * 4] = o;
        }
    }
}

// ---- edge pass 1: alpha[e,h] = scale * p_rel[h] * dot(q[dst,h,:], krel[src,h,:]); seg-max
// 8 lanes per (edge, head)
__global__ void edge_alpha(const int* __restrict__ src, const int* __restrict__ dst, int E,
                           const float* __restrict__ qd, const float* __restrict__ krel,
                           const float* __restrict__ prel, float scale,
                           float* __restrict__ alpha, unsigned* __restrict__ segmax)
{
    int t = blockIdx.x * 256 + threadIdx.x;
    int g = t >> 3, lane = t & 7;
    if (g >= E * 2) return;
    int e = g >> 1, h = g & 1;
    int s = src[e], d = dst[e];
    float4 q4 = *(const float4*)&qd[(long)d * 64 + h * 32 + lane * 4];
    float4 k4 = *(const float4*)&krel[(long)s * 64 + h * 32 + lane * 4];
    float p = q4.x * k4.x + q4.y * k4.y + q4.z * k4.z + q4.w * k4.w;
    p += __shfl_xor(p, 1);
    p += __shfl_xor(p, 2);
    p += __shfl_xor(p, 4);
    if (lane == 0) {
        float a = p * prel[h] * scale;
        alpha[e * 2 + h] = a;
        atomicMax(&segmax[d * 2 + h], enc_f(a));
    }
}

// ---- edge pass 2: segsum[d,h] += exp(alpha - m)
__global__ void edge_expsum(const int* __restrict__ dst, int E,
                            const float* __restrict__ alpha,
                            const unsigned* __restrict__ segmax, float* __restrict__ segsum)
{
    int t = blockIdx.x * 256 + threadIdx.x;
    if (t >= E * 2) return;
    int e = t >> 1, h = t & 1;
    int d = dst[e];
    float m = dec_f(segmax[d * 2 + h]);
    atomicAdd(&segsum[d * 2 + h], expf(alpha[t] - m));
}

// ---- edge pass 3: out[dst,h,:] += a * vrel[src,h,:]   (8 lanes per (e,h))
__global__ void edge_scatter(const int* __restrict__ src, const int* __restrict__ dst, int E,
                             const float* __restrict__ alpha, const unsigned* __restrict__ segmax,
                             const float* __restrict__ segsum, const float* __restrict__ vrel,
                             float* __restrict__ out)
{
    int t = blockIdx.x * 256 + threadIdx.x;
    int g = t >> 3, lane = t & 7;
    if (g >= E * 2) return;
    int e = g >> 1, h = g & 1;
    int s = src[e], d = dst[e];
    float m = dec_f(segmax[d * 2 + h]);
    float ss = segsum[d * 2 + h];
    float w = expf(alpha[e * 2 + h] - m) / (ss + 1e-16f);
    float4 v4 = *(const float4*)&vrel[(long)s * 64 + h * 32 + lane * 4];
    float* op = &out[(long)d * 64 + h * 32 + lane * 4];
    atomicAdd(op + 0, w * v4.x);
    atomicAdd(op + 1, w * v4.y);
    atomicAdd(op + 2, w * v4.z);
    atomicAdd(op + 3, w * v4.w);
}

// ---- link prediction: sigmoid(dot(zq[s], za[d])) over 64 dims, 8 lanes/pair
__global__ void pred_kernel(const int* __restrict__ src, const int* __restrict__ dst, int n,
                            const float* __restrict__ zq, const float* __restrict__ za,
                            float* __restrict__ out)
{
    int t = blockIdx.x * 256 + threadIdx.x;
    int g = t >> 3, lane = t & 7;
    if (g >= n) return;
    int s = src[g], d = dst[g];
    const float4* zs = (const float4*)&zq[(long)s * 64 + lane * 8];
    const float4* zd = (const float4*)&za[(long)d * 64 + lane * 8];
    float4 a0 = zs[0], a1 = zs[1], b0 = zd[0], b1 = zd[1];
    float p = a0.x * b0.x + a0.y * b0.y + a0.z * b0.z + a0.w * b0.w
            + a1.x * b1.x + a1.y * b1.y + a1.z * b1.z + a1.w * b1.w;
    p += __shfl_xor(p, 1);
    p += __shfl_xor(p, 2);
    p += __shfl_xor(p, 4);
    if (lane == 0) out[g] = 1.f / (1.f + expf(-p));
}

} // namespace

extern "C" void kernel_launch(void* const* d_in, const int* in_sizes, int n_in,
                              void* d_out, int out_size, void* d_ws, size_t ws_size,
                              hipStream_t stream)
{
    const float* xq    = (const float*)d_in[0];
    const float* xa    = (const float*)d_in[1];
    const float* xk    = (const float*)d_in[2];
    const float* lin_w = (const float*)d_in[3];
    const float* lin_b = (const float*)d_in[4];
    const float* k_w   = (const float*)d_in[5];
    const float* k_b   = (const float*)d_in[6];
    const float* q_w   = (const float*)d_in[7];
    const float* q_b   = (const float*)d_in[8];
    const float* v_w   = (const float*)d_in[9];
    const float* v_b   = (const float*)d_in[10];
    const float* a_w   = (const float*)d_in[11];
    const float* a_b   = (const float*)d_in[12];
    const float* a_rel = (const float*)d_in[13];
    const float* m_rel = (const float*)d_in[14];
    const float* p_rel = (const float*)d_in[15];
    const float* skip  = (const float*)d_in[16];
    const int* esrc[4] = {(const int*)d_in[17], (const int*)d_in[19], (const int*)d_in[21], (const int*)d_in[23]};
    const int* edst[4] = {(const int*)d_in[18], (const int*)d_in[20], (const int*)d_in[22], (const int*)d_in[24]};
    const int* pos_src = (const int*)d_in[25];
    const int* pos_dst = (const int*)d_in[26];
    const int* neg_src = (const int*)d_in[27];
    const int* neg_dst = (const int*)d_in[28];

    float* ws   = (float*)d_ws;
    float* outp = (float*)d_out;

    // zero attention accumulator + segment max/sum (encoded 0 < any finite enc_f value)
    hipMemsetAsync(ws + OUT_OFF, 0, 32000000L * sizeof(float), stream);
    hipMemsetAsync(ws + SMAX_OFF, 0, 2400000L * sizeof(float), stream);

    fuse_weights<<<8, 256, 0, stream>>>(k_w, k_b, v_w, v_b, a_rel, m_rel, ws + WF_OFF);

    const float* xin[3] = {xq, xa, xk};
    const int  cnt[3]  = {NQn, NAn, NKn};
    const long noff[3] = {0, NQn, NQn + NAn};

    // xs = relu(x @ lin_w + lin_b)
    for (int t = 0; t < 3; ++t)
        node_gemm<128, false, true, false><<<(cnt[t] + 63) / 64, 256, 0, stream>>>(
            xin[t], lin_w + (long)t * 128 * 64, lin_b + t * 64,
            ws + XS_OFF + noff[t] * 64, cnt[t], nullptr, nullptr);

    // q = xs @ q_w + q_b
    for (int t = 0; t < 3; ++t)
        node_gemm<64, false, false, false><<<(cnt[t] + 63) / 64, 256, 0, stream>>>(
            ws + XS_OFF + noff[t] * 64, q_w + (long)t * 64 * 64, q_b + t * 64,
            ws + Q_OFF + noff[t] * 64, cnt[t], nullptr, nullptr);

    const int  stt[4]  = {2, 0, 0, 1};
    const int  dtt[4]  = {0, 2, 1, 0};
    const int  Es[4]   = {800000, 800000, 400000, 400000};
    const long soff[4] = {0, 100000, 300000, 500000};  // seg array node offsets per relation
    const float scale  = 0.17677669529663687f;         // 1/sqrt(32)

    for (int r = 0; r < 4; ++r) {
        const int st = stt[r], dt = dtt[r];
        node_gemm<64, false, false, false><<<(cnt[st] + 63) / 64, 256, 0, stream>>>(
            ws + XS_OFF + noff[st] * 64, ws + WF_OFF + (long)(r * 2 + 0) * 4160,
            ws + WF_OFF + (long)(r * 2 + 0) * 4160 + 4096, ws + KREL_OFF, cnt[st], nullptr, nullptr);
        node_gemm<64, false, false, false><<<(cnt[st] + 63) / 64, 256, 0, stream>>>(
            ws + XS_OFF + noff[st] * 64, ws + WF_OFF + (long)(r * 2 + 1) * 4160,
            ws + WF_OFF + (long)(r * 2 + 1) * 4160 + 4096, ws + VREL_OFF, cnt[st], nullptr, nullptr);

        unsigned* smax = (unsigned*)(ws + SMAX_OFF) + soff[r] * 2;
        float*    ssum = ws + SSUM_OFF + soff[r] * 2;

        edge_alpha<<<(Es[r] * 16 + 255) / 256, 256, 0, stream>>>(
            esrc[r], edst[r], Es[r], ws + Q_OFF + noff[dt] * 64, ws + KREL_OFF,
            p_rel + r * 2, scale, ws + ALPHA_OFF, smax);
        edge_expsum<<<(Es[r] * 2 + 255) / 256, 256, 0, stream>>>(
            edst[r], Es[r], ws + ALPHA_OFF, smax, ssum);
        edge_scatter<<<(Es[r] * 16 + 255) / 256, 256, 0, stream>>>(
            esrc[r], edst[r], Es[r], ws + ALPHA_OFF, smax, ssum,
            ws + VREL_OFF, ws + OUT_OFF + noff[dt] * 64);
    }

    // z = beta * (gelu(out) @ a_w + a_b) + (1-beta) * xs   -> straight into d_out
    const long zoff[3] = {200000L, 200000L + 6400000L, 200000L + 6400000L + 12800000L};
    for (int t = 0; t < 3; ++t)
        node_gemm<64, true, false, true><<<(cnt[t] + 63) / 64, 256, 0, stream>>>(
            ws + OUT_OFF + noff[t] * 64, a_w + (long)t * 64 * 64, a_b + t * 64,
            outp + zoff[t], cnt[t], ws + XS_OFF + noff[t] * 64, skip + t);

    // link predictions read zq/za back out of d_out
    pred_kernel<<<(EPc * 8 + 255) / 256, 256, 0, stream>>>(
        pos_src, pos_dst, EPc, outp + 200000, outp + 6600000, outp);
    pred_kernel<<<(ENc * 8 + 255) / 256, 256, 0, stream>>>(
        neg_src, neg_dst, ENc, outp + 200000, outp + 6600000, outp + EPc);
}

// Round 2
// 1595.865 us; speedup vs baseline: 2.0636x; 2.0636x over previous
//
#include <hip/hip_runtime.h>
#include <math.h>

namespace {

constexpr int NQn = 100000, NAn = 200000, NKn = 200000;
constexpr int EPc = 100000, ENc = 100000;

// workspace layout (float element offsets)
constexpr long XS_OFF   = 0;            // 32,000,000 (xs: q,a,k types concatenated, 64/node)
constexpr long Q_OFF    = 32000000;     // 32,000,000
constexpr long OUT_OFF  = 64000000;     // 32,000,000 (attention accum)
constexpr long KREL_OFF = 96000000;     // 12,800,000 (per-relation reuse)
constexpr long VREL_OFF = 108800000;    // 12,800,000
constexpr long WF_OFF   = 121600000;    // 8*4160 fused rel weights (W 64x64 + b 64)
constexpr long INT_OFF  = 121700000;    // int region below
// int region (int element offsets within (int*)(ws + INT_OFF)):
constexpr long DEG_I  = 0;        // 200,000
constexpr long CUR_I  = 200000;   // 200,000
constexpr long OFFS_I = 400000;   // 200,001
constexpr long PART_I = 600064;   // 256
constexpr long CSRC_I = 600320;   // 800,000
// region end ~123.1M floats = 492 MB total ws use

__device__ inline float gelu_f(float x) {
    return 0.5f * x * (1.0f + erff(x * 0.7071067811865475f));
}

// ---- fused relation weights: W'[d][h*32+e] = sum_c w[d][h*32+c]*rel[h][c][e]; b' likewise
__global__ void fuse_weights(const float* __restrict__ kw, const float* __restrict__ kb,
                             const float* __restrict__ vw, const float* __restrict__ vb,
                             const float* __restrict__ a_rel, const float* __restrict__ m_rel,
                             float* __restrict__ wf)
{
    const int r = blockIdx.x >> 1, which = blockIdx.x & 1;
    const int st_tab[4] = {2, 0, 0, 1};
    const int st = st_tab[r];
    const float* w   = (which ? vw : kw) + st * 64 * 64;
    const float* b   = (which ? vb : kb) + st * 64;
    const float* rel = (which ? m_rel : a_rel) + r * 2 * 32 * 32;
    float* out = wf + (long)blockIdx.x * 4160;
    const int tid = threadIdx.x;
    for (int idx = tid; idx < 4096; idx += 256) {
        int d = idx >> 6, col = idx & 63;
        int h = col >> 5, e = col & 31;
        float s = 0.f;
        #pragma unroll
        for (int c = 0; c < 32; ++c) s += w[d * 64 + h * 32 + c] * rel[h * 1024 + c * 32 + e];
        out[idx] = s;
    }
    if (tid < 64) {
        int h = tid >> 5, e = tid & 31;
        float s = 0.f;
        #pragma unroll
        for (int c = 0; c < 32; ++c) s += b[h * 32 + c] * rel[h * 1024 + c * 32 + e];
        out[4096 + tid] = s;
    }
}

// ---- generic per-node GEMM: Y = act_out( act_in(X) @ W + b ), optional skip-mix
template<int K, bool IN_GELU, bool OUT_RELU, bool MIX>
__global__ void __launch_bounds__(256)
node_gemm(const float* __restrict__ X, const float* __restrict__ W,
          const float* __restrict__ bias, float* __restrict__ Y, int n,
          const float* __restrict__ res, const float* __restrict__ skipv)
{
    __shared__ float ldsW[K * 64];
    __shared__ float ldsX[K * 64];   // [c][node], XOR-swizzled on node index
    const int tid = threadIdx.x;
    const int n0 = blockIdx.x * 64;

    for (int idx = tid; idx < K * 64; idx += 256) ldsW[idx] = W[idx];
    for (int idx = tid; idx < K * 64; idx += 256) {
        int r = idx / K, c = idx - r * K;
        int node = n0 + r; if (node > n - 1) node = n - 1;
        float v = X[(long)node * K + c];
        if (IN_GELU) v = gelu_f(v);
        ldsX[c * 64 + (r ^ (c & 31))] = v;
    }
    __syncthreads();

    const int j = tid & 15;
    const int i = tid >> 4;
    float acc[4][4] = {};
    #pragma unroll 4
    for (int d = 0; d < K; ++d) {
        float4 wv = *(const float4*)&ldsW[d * 64 + j * 4];
        float xv[4];
        #pragma unroll
        for (int k = 0; k < 4; ++k) xv[k] = ldsX[d * 64 + ((i * 4 + k) ^ (d & 31))];
        #pragma unroll
        for (int k = 0; k < 4; ++k) {
            acc[k][0] += xv[k] * wv.x; acc[k][1] += xv[k] * wv.y;
            acc[k][2] += xv[k] * wv.z; acc[k][3] += xv[k] * wv.w;
        }
    }

    const float4 bv = *(const float4*)&bias[j * 4];
    float beta = 0.f;
    if (MIX) beta = 1.f / (1.f + expf(-skipv[0]));
    #pragma unroll
    for (int k = 0; k < 4; ++k) {
        int node = n0 + i * 4 + k;
        if (node < n) {
            float4 o;
            o.x = acc[k][0] + bv.x; o.y = acc[k][1] + bv.y;
            o.z = acc[k][2] + bv.z; o.w = acc[k][3] + bv.w;
            if (OUT_RELU) {
                o.x = fmaxf(o.x, 0.f); o.y = fmaxf(o.y, 0.f);
                o.z = fmaxf(o.z, 0.f); o.w = fmaxf(o.w, 0.f);
            }
            if (MIX) {
                float4 rv = *(const float4*)&res[(long)node * 64 + j * 4];
                o.x = beta * o.x + (1.f - beta) * rv.x;
                o.y = beta * o.y + (1.f - beta) * rv.y;
                o.z = beta * o.z + (1.f - beta) * rv.z;
                o.w = beta * o.w + (1.f - beta) * rv.w;
            }
            *(float4*)&Y[(long)node * 64 + j * 4] = o;
        }
    }
}

// ---- CSR build -------------------------------------------------------------
__global__ void csr_count(const int* __restrict__ dst, int E, int* __restrict__ deg)
{
    int i = blockIdx.x * 256 + threadIdx.x;
    if (i < E) atomicAdd(&deg[dst[i]], 1);
}

__global__ void scan1(const int* __restrict__ in, int* __restrict__ out,
                      int* __restrict__ part, int n)
{
    __shared__ int lds[256];
    const int tid = threadIdx.x;
    const int base = blockIdx.x * 1024 + tid * 4;
    int v[4];
    #pragma unroll
    for (int k = 0; k < 4; ++k) v[k] = (base + k < n) ? in[base + k] : 0;
    int tsum = v[0] + v[1] + v[2] + v[3];
    lds[tid] = tsum;
    __syncthreads();
    for (int off = 1; off < 256; off <<= 1) {
        int t = (tid >= off) ? lds[tid - off] : 0;
        __syncthreads();
        lds[tid] += t;
        __syncthreads();
    }
    int excl = lds[tid] - tsum;
    #pragma unroll
    for (int k = 0; k < 4; ++k) {
        if (base + k < n) out[base + k] = excl;
        excl += v[k];
    }
    if (tid == 255) part[blockIdx.x] = lds[255];
}

__global__ void scan2(int* __restrict__ part, int nb)
{
    __shared__ int lds[256];
    const int tid = threadIdx.x;
    int v = (tid < nb) ? part[tid] : 0;
    lds[tid] = v;
    __syncthreads();
    for (int off = 1; off < 256; off <<= 1) {
        int t = (tid >= off) ? lds[tid - off] : 0;
        __syncthreads();
        lds[tid] += t;
        __syncthreads();
    }
    if (tid < nb) part[tid] = lds[tid] - v;   // exclusive
}

__global__ void scan3(int* __restrict__ off, const int* __restrict__ part, int n, int E)
{
    int i = blockIdx.x * 256 + threadIdx.x;
    if (i < n) off[i] += part[i >> 10];
    if (i == 0) off[n] = E;
}

__global__ void csr_fill(const int* __restrict__ src, const int* __restrict__ dst, int E,
                         const int* __restrict__ off, int* __restrict__ cur,
                         int* __restrict__ csrc)
{
    int i = blockIdx.x * 256 + threadIdx.x;
    if (i < E) {
        int d = dst[i];
        int slot = off[d] + atomicAdd(&cur[d], 1);
        csrc[slot] = src[i];
    }
}

// ---- fused attention: one wave per destination node, flash-style online softmax
__global__ void __launch_bounds__(256)
attn_fused(const int* __restrict__ off, const int* __restrict__ csrc,
           const float* __restrict__ q, const float* __restrict__ krel,
           const float* __restrict__ vrel, const float* __restrict__ prel,
           float scale, float* __restrict__ out, int ndst)
{
    const int wid = blockIdx.x * 4 + (threadIdx.x >> 6);
    const int lane = threadIdx.x & 63;
    if (wid >= ndst) return;
    const int begin = off[wid], end = off[wid + 1];
    if (begin == end) return;                   // empty segment: out stays as accumulated

    const int h = lane >> 5;
    const float qv = q[(long)wid * 64 + lane];
    const float pscale = prel[h] * scale;

    float m = -INFINITY, ssum = 0.f, acc = 0.f;
    for (int t = begin; t < end; ++t) {
        int s = csrc[t];                        // wave-uniform scalar load
        float kv = krel[(long)s * 64 + lane];   // coalesced 256B wave load
        float p = qv * kv;
        p += __shfl_xor(p, 1);
        p += __shfl_xor(p, 2);
        p += __shfl_xor(p, 4);
        p += __shfl_xor(p, 8);
        p += __shfl_xor(p, 16);                 // all 32 lanes of each head-half hold dot
        float a = p * pscale;
        float mn = fmaxf(m, a);
        float corr = __expf(m - mn);            // 0 on first edge (m = -inf)
        float w = __expf(a - mn);
        ssum = ssum * corr + w;
        m = mn;
        float vv = vrel[(long)s * 64 + lane];   // coalesced 256B wave load
        acc = acc * corr + w * vv;
    }
    out[(long)wid * 64 + lane] += acc / (ssum + 1e-16f);
}

// ---- link prediction: sigmoid(dot(zq[s], za[d])) over 64 dims, 8 lanes/pair
__global__ void pred_kernel(const int* __restrict__ src, const int* __restrict__ dst, int n,
                            const float* __restrict__ zq, const float* __restrict__ za,
                            float* __restrict__ out)
{
    int t = blockIdx.x * 256 + threadIdx.x;
    int g = t >> 3, lane = t & 7;
    if (g >= n) return;
    int s = src[g], d = dst[g];
    const float4* zs = (const float4*)&zq[(long)s * 64 + lane * 8];
    const float4* zd = (const float4*)&za[(long)d * 64 + lane * 8];
    float4 a0 = zs[0], a1 = zs[1], b0 = zd[0], b1 = zd[1];
    float p = a0.x * b0.x + a0.y * b0.y + a0.z * b0.z + a0.w * b0.w
            + a1.x * b1.x + a1.y * b1.y + a1.z * b1.z + a1.w * b1.w;
    p += __shfl_xor(p, 1);
    p += __shfl_xor(p, 2);
    p += __shfl_xor(p, 4);
    if (lane == 0) out[g] = 1.f / (1.f + expf(-p));
}

} // namespace

extern "C" void kernel_launch(void* const* d_in, const int* in_sizes, int n_in,
                              void* d_out, int out_size, void* d_ws, size_t ws_size,
                              hipStream_t stream)
{
    const float* xq    = (const float*)d_in[0];
    const float* xa    = (const float*)d_in[1];
    const float* xk    = (const float*)d_in[2];
    const float* lin_w = (const float*)d_in[3];
    const float* lin_b = (const float*)d_in[4];
    const float* k_w   = (const float*)d_in[5];
    const float* k_b   = (const float*)d_in[6];
    const float* q_w   = (const float*)d_in[7];
    const float* q_b   = (const float*)d_in[8];
    const float* v_w   = (const float*)d_in[9];
    const float* v_b   = (const float*)d_in[10];
    const float* a_w   = (const float*)d_in[11];
    const float* a_b   = (const float*)d_in[12];
    const float* a_rel = (const float*)d_in[13];
    const float* m_rel = (const float*)d_in[14];
    const float* p_rel = (const float*)d_in[15];
    const float* skip  = (const float*)d_in[16];
    const int* esrc[4] = {(const int*)d_in[17], (const int*)d_in[19], (const int*)d_in[21], (const int*)d_in[23]};
    const int* edst[4] = {(const int*)d_in[18], (const int*)d_in[20], (const int*)d_in[22], (const int*)d_in[24]};
    const int* pos_src = (const int*)d_in[25];
    const int* pos_dst = (const int*)d_in[26];
    const int* neg_src = (const int*)d_in[27];
    const int* neg_dst = (const int*)d_in[28];

    float* ws   = (float*)d_ws;
    float* outp = (float*)d_out;
    int*   wi   = (int*)(ws + INT_OFF);

    // zero attention accumulator
    hipMemsetAsync(ws + OUT_OFF, 0, 32000000L * sizeof(float), stream);

    fuse_weights<<<8, 256, 0, stream>>>(k_w, k_b, v_w, v_b, a_rel, m_rel, ws + WF_OFF);

    const float* xin[3] = {xq, xa, xk};
    const int  cnt[3]  = {NQn, NAn, NKn};
    const long noff[3] = {0, NQn, NQn + NAn};

    // xs = relu(x @ lin_w + lin_b)
    for (int t = 0; t < 3; ++t)
        node_gemm<128, false, true, false><<<(cnt[t] + 63) / 64, 256, 0, stream>>>(
            xin[t], lin_w + (long)t * 128 * 64, lin_b + t * 64,
            ws + XS_OFF + noff[t] * 64, cnt[t], nullptr, nullptr);

    // q = xs @ q_w + q_b
    for (int t = 0; t < 3; ++t)
        node_gemm<64, false, false, false><<<(cnt[t] + 63) / 64, 256, 0, stream>>>(
            ws + XS_OFF + noff[t] * 64, q_w + (long)t * 64 * 64, q_b + t * 64,
            ws + Q_OFF + noff[t] * 64, cnt[t], nullptr, nullptr);

    const int  stt[4] = {2, 0, 0, 1};
    const int  dtt[4] = {0, 2, 1, 0};
    const int  Es[4]  = {800000, 800000, 400000, 400000};
    const float scale = 0.17677669529663687f;   // 1/sqrt(32)

    for (int r = 0; r < 4; ++r) {
        const int st = stt[r], dt = dtt[r];
        const int ndst = cnt[dt];
        const int E = Es[r];

        // krel / vrel node-level transforms (fused k_w*a_rel / v_w*m_rel weights)
        node_gemm<64, false, false, false><<<(cnt[st] + 63) / 64, 256, 0, stream>>>(
            ws + XS_OFF + noff[st] * 64, ws + WF_OFF + (long)(r * 2 + 0) * 4160,
            ws + WF_OFF + (long)(r * 2 + 0) * 4160 + 4096, ws + KREL_OFF, cnt[st], nullptr, nullptr);
        node_gemm<64, false, false, false><<<(cnt[st] + 63) / 64, 256, 0, stream>>>(
            ws + XS_OFF + noff[st] * 64, ws + WF_OFF + (long)(r * 2 + 1) * 4160,
            ws + WF_OFF + (long)(r * 2 + 1) * 4160 + 4096, ws + VREL_OFF, cnt[st], nullptr, nullptr);

        // CSR build (deg -> exclusive scan -> fill)
        hipMemsetAsync(wi + DEG_I, 0, 400000L * sizeof(int), stream);   // deg + cursor
        csr_count<<<(E + 255) / 256, 256, 0, stream>>>(edst[r], E, wi + DEG_I);
        const int nb = (ndst + 1023) / 1024;
        scan1<<<nb, 256, 0, stream>>>(wi + DEG_I, wi + OFFS_I, wi + PART_I, ndst);
        scan2<<<1, 256, 0, stream>>>(wi + PART_I, nb);
        scan3<<<(ndst + 255) / 256, 256, 0, stream>>>(wi + OFFS_I, wi + PART_I, ndst, E);
        csr_fill<<<(E + 255) / 256, 256, 0, stream>>>(esrc[r], edst[r], E,
                                                      wi + OFFS_I, wi + CUR_I, wi + CSRC_I);

        // fused attention: one wave per destination
        attn_fused<<<(ndst + 3) / 4, 256, 0, stream>>>(
            wi + OFFS_I, wi + CSRC_I, ws + Q_OFF + noff[dt] * 64,
            ws + KREL_OFF, ws + VREL_OFF, p_rel + r * 2, scale,
            ws + OUT_OFF + noff[dt] * 64, ndst);
    }

    // z = beta * (gelu(out) @ a_w + a_b) + (1-beta) * xs   -> straight into d_out
    const long zoff[3] = {200000L, 200000L + 6400000L, 200000L + 6400000L + 12800000L};
    for (int t = 0; t < 3; ++t)
        node_gemm<64, true, false, true><<<(cnt[t] + 63) / 64, 256, 0, stream>>>(
            ws + OUT_OFF + noff[t] * 64, a_w + (long)t * 64 * 64, a_b + t * 64,
            outp + zoff[t], cnt[t], ws + XS_OFF + noff[t] * 64, skip + t);

    // link predictions read zq/za back out of d_out
    pred_kernel<<<(EPc * 8 + 255) / 256, 256, 0, stream>>>(
        pos_src, pos_dst, EPc, outp + 200000, outp + 6600000, outp);
    pred_kernel<<<(ENc * 8 + 255) / 256, 256, 0, stream>>>(
        neg_src, neg_dst, ENc, outp + 200000, outp + 6600000, outp + EPc);
}

// Round 3
// 1403.878 us; speedup vs baseline: 2.3458x; 1.1368x over previous
//
#include <hip/hip_runtime.h>
#include <math.h>

namespace {

constexpr int NQn = 100000, NAn = 200000, NKn = 200000;
constexpr int EPc = 100000, ENc = 100000;
constexpr int ETOT = 2400000, NSEG = 600000;

// workspace layout (float element offsets)
constexpr long XS_OFF  = 0;             // 32,000,000
constexpr long Q_OFF   = 32000000;      // 32,000,000
constexpr long OUT_OFF = 64000000;      // 32,000,000
constexpr long KV_OFF  = 96000000;      // 12,800,000 floats (25.6M bf16, per-relation reuse)
constexpr long WF_OFF  = 108800000;     // 4*8320 fused interleaved rel weights
constexpr long INT_OFF = 108900000;     // int region below
// int offsets within (int*)(ws + INT_OFF):
constexpr long DEG_I  = 0;          // 600,000
constexpr long CUR_I  = 600000;     // 600,000
constexpr long OFFS_I = 1200000;    // 600,001 (pad to 600,064)
constexpr long PART_I = 1800064;    // 1024
constexpr long CSRC_I = 1801088;    // 2,400,000
// end ~113.1M floats = 452 MB

__device__ inline float gelu_f(float x) {
    return 0.5f * x * (1.0f + erff(x * 0.7071067811865475f));
}
__device__ inline float bf2f(unsigned short u) {
    return __uint_as_float(((unsigned)u) << 16);
}
__device__ inline unsigned short f2bf(float f) {
    unsigned u = __float_as_uint(f);
    return (unsigned short)((u + 0x7fffu + ((u >> 16) & 1u)) >> 16);
}

// ---- fused interleaved relation weights: col c of 128 -> (i=c>>1, which=c&1)
// W'[d][c] = sum_c32 w[d][h*32+c32] * rel[h][c32][e]   (i = h*32+e)
__global__ void fuse_weights(const float* __restrict__ kw, const float* __restrict__ kb,
                             const float* __restrict__ vw, const float* __restrict__ vb,
                             const float* __restrict__ a_rel, const float* __restrict__ m_rel,
                             float* __restrict__ wf)
{
    const int r = blockIdx.x;
    const int st_tab[4] = {2, 0, 0, 1};
    const int st = st_tab[r];
    float* out = wf + (long)r * 8320;
    const int tid = threadIdx.x;
    for (int idx = tid; idx < 8192; idx += 256) {
        int d = idx >> 7, c = idx & 127;
        int i = c >> 1, which = c & 1;
        int h = i >> 5, e = i & 31;
        const float* w   = (which ? vw : kw) + st * 4096;
        const float* rel = (which ? m_rel : a_rel) + r * 2048;
        float s = 0.f;
        #pragma unroll
        for (int c32 = 0; c32 < 32; ++c32)
            s += w[d * 64 + h * 32 + c32] * rel[h * 1024 + c32 * 32 + e];
        out[idx] = s;
    }
    for (int idx = tid; idx < 128; idx += 256) {
        int i = idx >> 1, which = idx & 1;
        int h = i >> 5, e = i & 31;
        const float* b   = (which ? vb : kb) + st * 64;
        const float* rel = (which ? m_rel : a_rel) + r * 2048;
        float s = 0.f;
        #pragma unroll
        for (int c32 = 0; c32 < 32; ++c32)
            s += b[h * 32 + c32] * rel[h * 1024 + c32 * 32 + e];
        out[8192 + idx] = s;
    }
}

// ---- generic per-node GEMM: Y = act_out( act_in(X) @ W + b ), optional skip-mix
template<int K, bool IN_GELU, bool OUT_RELU, bool MIX>
__global__ void __launch_bounds__(256)
node_gemm(const float* __restrict__ X, const float* __restrict__ W,
          const float* __restrict__ bias, float* __restrict__ Y, int n,
          const float* __restrict__ res, const float* __restrict__ skipv)
{
    __shared__ float ldsW[K * 64];
    __shared__ float ldsX[K * 64];
    const int tid = threadIdx.x;
    const int n0 = blockIdx.x * 64;

    for (int idx = tid; idx < K * 64; idx += 256) ldsW[idx] = W[idx];
    for (int idx = tid; idx < K * 64; idx += 256) {
        int r = idx / K, c = idx - r * K;
        int node = n0 + r; if (node > n - 1) node = n - 1;
        float v = X[(long)node * K + c];
        if (IN_GELU) v = gelu_f(v);
        ldsX[c * 64 + (r ^ (c & 31))] = v;
    }
    __syncthreads();

    const int j = tid & 15;
    const int i = tid >> 4;
    float acc[4][4] = {};
    #pragma unroll 4
    for (int d = 0; d < K; ++d) {
        float4 wv = *(const float4*)&ldsW[d * 64 + j * 4];
        float xv[4];
        #pragma unroll
        for (int k = 0; k < 4; ++k) xv[k] = ldsX[d * 64 + ((i * 4 + k) ^ (d & 31))];
        #pragma unroll
        for (int k = 0; k < 4; ++k) {
            acc[k][0] += xv[k] * wv.x; acc[k][1] += xv[k] * wv.y;
            acc[k][2] += xv[k] * wv.z; acc[k][3] += xv[k] * wv.w;
        }
    }

    const float4 bv = *(const float4*)&bias[j * 4];
    float beta = 0.f;
    if (MIX) beta = 1.f / (1.f + expf(-skipv[0]));
    #pragma unroll
    for (int k = 0; k < 4; ++k) {
        int node = n0 + i * 4 + k;
        if (node < n) {
            float4 o;
            o.x = acc[k][0] + bv.x; o.y = acc[k][1] + bv.y;
            o.z = acc[k][2] + bv.z; o.w = acc[k][3] + bv.w;
            if (OUT_RELU) {
                o.x = fmaxf(o.x, 0.f); o.y = fmaxf(o.y, 0.f);
                o.z = fmaxf(o.z, 0.f); o.w = fmaxf(o.w, 0.f);
            }
            if (MIX) {
                float4 rv = *(const float4*)&res[(long)node * 64 + j * 4];
                o.x = beta * o.x + (1.f - beta) * rv.x;
                o.y = beta * o.y + (1.f - beta) * rv.y;
                o.z = beta * o.z + (1.f - beta) * rv.z;
                o.w = beta * o.w + (1.f - beta) * rv.w;
            }
            *(float4*)&Y[(long)node * 64 + j * 4] = o;
        }
    }
}

// ---- fused kv GEMM: KV[node][c] = bf16( xs[node] @ W'[.,c] + b'[c] ), 128 cols
__global__ void __launch_bounds__(256)
kv_gemm(const float* __restrict__ X, const float* __restrict__ W,
        const float* __restrict__ bias, unsigned short* __restrict__ KV, int n)
{
    __shared__ float ldsW[64 * 128];
    __shared__ float ldsX[64 * 64];
    const int tid = threadIdx.x;
    const int n0 = blockIdx.x * 64;

    for (int idx = tid; idx < 8192; idx += 256) ldsW[idx] = W[idx];
    for (int idx = tid; idx < 4096; idx += 256) {
        int r = idx >> 6, c = idx & 63;
        int node = n0 + r; if (node > n - 1) node = n - 1;
        ldsX[c * 64 + (r ^ (c & 31))] = X[(long)node * 64 + c];
    }
    __syncthreads();

    const int j = tid & 31;   // 32 col-groups x 4 cols
    const int i = tid >> 5;   // 8 node-groups x 8 nodes
    float acc[8][4] = {};
    #pragma unroll 4
    for (int d = 0; d < 64; ++d) {
        float4 wv = *(const float4*)&ldsW[d * 128 + j * 4];
        #pragma unroll
        for (int k = 0; k < 8; ++k) {
            float xv = ldsX[d * 64 + ((i * 8 + k) ^ (d & 31))];
            acc[k][0] += xv * wv.x; acc[k][1] += xv * wv.y;
            acc[k][2] += xv * wv.z; acc[k][3] += xv * wv.w;
        }
    }

    const float4 bv = *(const float4*)&bias[j * 4];
    #pragma unroll
    for (int k = 0; k < 8; ++k) {
        int node = n0 + i * 8 + k;
        if (node < n) {
            ushort4 o;
            o.x = f2bf(acc[k][0] + bv.x); o.y = f2bf(acc[k][1] + bv.y);
            o.z = f2bf(acc[k][2] + bv.z); o.w = f2bf(acc[k][3] + bv.w);
            *(ushort4*)&KV[(long)node * 128 + j * 4] = o;
        }
    }
}

// ---- CSR build, all 4 relations at once ------------------------------------
// edge id space: [0,800k) r0, [800k,1.6M) r1, [1.6M,2M) r2, [2M,2.4M) r3
// seg bases: {0, 100000, 300000, 500000}
__global__ void csr_count_all(const int* __restrict__ d0, const int* __restrict__ d1,
                              const int* __restrict__ d2, const int* __restrict__ d3,
                              int* __restrict__ deg)
{
    int gid = blockIdx.x * 256 + threadIdx.x;
    if (gid < 800000)       atomicAdd(&deg[d0[gid]], 1);
    else if (gid < 1600000) atomicAdd(&deg[100000 + d1[gid - 800000]], 1);
    else if (gid < 2000000) atomicAdd(&deg[300000 + d2[gid - 1600000]], 1);
    else if (gid < 2400000) atomicAdd(&deg[500000 + d3[gid - 2000000]], 1);
}

__global__ void csr_fill_all(const int* __restrict__ s0, const int* __restrict__ d0,
                             const int* __restrict__ s1, const int* __restrict__ d1,
                             const int* __restrict__ s2, const int* __restrict__ d2,
                             const int* __restrict__ s3, const int* __restrict__ d3,
                             const int* __restrict__ off, int* __restrict__ cur,
                             int* __restrict__ csrc)
{
    int gid = blockIdx.x * 256 + threadIdx.x;
    int seg, s;
    if (gid < 800000)       { seg = d0[gid] ;          s = s0[gid]; }
    else if (gid < 1600000) { seg = 100000 + d1[gid - 800000];  s = s1[gid - 800000]; }
    else if (gid < 2000000) { seg = 300000 + d2[gid - 1600000]; s = s2[gid - 1600000]; }
    else if (gid < 2400000) { seg = 500000 + d3[gid - 2000000]; s = s3[gid - 2000000]; }
    else return;
    int slot = off[seg] + atomicAdd(&cur[seg], 1);
    csrc[slot] = s;
}

__global__ void scan1(const int* __restrict__ in, int* __restrict__ out,
                      int* __restrict__ part, int n)
{
    __shared__ int lds[256];
    const int tid = threadIdx.x;
    const int base = blockIdx.x * 1024 + tid * 4;
    int v[4];
    #pragma unroll
    for (int k = 0; k < 4; ++k) v[k] = (base + k < n) ? in[base + k] : 0;
    int tsum = v[0] + v[1] + v[2] + v[3];
    lds[tid] = tsum;
    __syncthreads();
    for (int off = 1; off < 256; off <<= 1) {
        int t = (tid >= off) ? lds[tid - off] : 0;
        __syncthreads();
        lds[tid] += t;
        __syncthreads();
    }
    int excl = lds[tid] - tsum;
    #pragma unroll
    for (int k = 0; k < 4; ++k) {
        if (base + k < n) out[base + k] = excl;
        excl += v[k];
    }
    if (tid == 255) part[blockIdx.x] = lds[255];
}

__global__ void scan2(int* __restrict__ part, int nb)   // nb <= 1024
{
    __shared__ int lds[256];
    const int tid = threadIdx.x;
    const int base = tid * 4;
    int v[4];
    #pragma unroll
    for (int k = 0; k < 4; ++k) v[k] = (base + k < nb) ? part[base + k] : 0;
    int tsum = v[0] + v[1] + v[2] + v[3];
    lds[tid] = tsum;
    __syncthreads();
    for (int off = 1; off < 256; off <<= 1) {
        int t = (tid >= off) ? lds[tid - off] : 0;
        __syncthreads();
        lds[tid] += t;
        __syncthreads();
    }
    int excl = lds[tid] - tsum;
    #pragma unroll
    for (int k = 0; k < 4; ++k) {
        if (base + k < nb) part[base + k] = excl;
        excl += v[k];
    }
}

__global__ void scan3(int* __restrict__ off, const int* __restrict__ part, int n, int E)
{
    int i = blockIdx.x * 256 + threadIdx.x;
    if (i < n) off[i] += part[i >> 10];
    if (i == 0) off[n] = E;
}

// ---- fused attention: one wave per destination, online softmax, bf16 kv gather
template<bool ACCUM>
__global__ void __launch_bounds__(256)
attn_fused(const int* __restrict__ off, const int* __restrict__ csrc,
           const float* __restrict__ q, const unsigned short* __restrict__ kv,
           const float* __restrict__ prel, float scale, float* __restrict__ out, int ndst)
{
    const int wid = blockIdx.x * 4 + (threadIdx.x >> 6);
    const int lane = threadIdx.x & 63;
    if (wid >= ndst) return;
    const int begin = off[wid], end = off[wid + 1];
    const long obase = (long)wid * 64 + lane;
    if (begin == end) { if (!ACCUM) out[obase] = 0.f; return; }

    const int h = lane >> 5;
    const float qv = q[obase];
    const float pscale = prel[h] * scale;

    float m = -INFINITY, ssum = 0.f, acc = 0.f;
    int s0 = csrc[begin];
    ushort2 kvc = ((const ushort2*)(kv + (long)s0 * 128))[lane];
    for (int t = begin; t < end; ++t) {
        ushort2 cur = kvc;
        if (t + 1 < end) {                       // prefetch next row under the reduce chain
            int s2 = csrc[t + 1];
            kvc = ((const ushort2*)(kv + (long)s2 * 128))[lane];
        }
        float p = qv * bf2f(cur.x);
        p += __shfl_xor(p, 1);
        p += __shfl_xor(p, 2);
        p += __shfl_xor(p, 4);
        p += __shfl_xor(p, 8);
        p += __shfl_xor(p, 16);
        float a = p * pscale;
        float mn = fmaxf(m, a);
        float corr = __expf(m - mn);
        float w = __expf(a - mn);
        ssum = ssum * corr + w;
        m = mn;
        acc = acc * corr + w * bf2f(cur.y);
    }
    float res = acc / (ssum + 1e-16f);
    if (ACCUM) out[obase] += res;
    else       out[obase] = res;
}

// ---- link prediction
__global__ void pred_kernel(const int* __restrict__ src, const int* __restrict__ dst, int n,
                            const float* __restrict__ zq, const float* __restrict__ za,
                            float* __restrict__ out)
{
    int t = blockIdx.x * 256 + threadIdx.x;
    int g = t >> 3, lane = t & 7;
    if (g >= n) return;
    int s = src[g], d = dst[g];
    const float4* zs = (const float4*)&zq[(long)s * 64 + lane * 8];
    const float4* zd = (const float4*)&za[(long)d * 64 + lane * 8];
    float4 a0 = zs[0], a1 = zs[1], b0 = zd[0], b1 = zd[1];
    float p = a0.x * b0.x + a0.y * b0.y + a0.z * b0.z + a0.w * b0.w
            + a1.x * b1.x + a1.y * b1.y + a1.z * b1.z + a1.w * b1.w;
    p += __shfl_xor(p, 1);
    p += __shfl_xor(p, 2);
    p += __shfl_xor(p, 4);
    if (lane == 0) out[g] = 1.f / (1.f + expf(-p));
}

} // namespace

extern "C" void kernel_launch(void* const* d_in, const int* in_sizes, int n_in,
                              void* d_out, int out_size, void* d_ws, size_t ws_size,
                              hipStream_t stream)
{
    const float* xq    = (const float*)d_in[0];
    const float* xa    = (const float*)d_in[1];
    const float* xk    = (const float*)d_in[2];
    const float* lin_w = (const float*)d_in[3];
    const float* lin_b = (const float*)d_in[4];
    const float* k_w   = (const float*)d_in[5];
    const float* k_b   = (const float*)d_in[6];
    const float* q_w   = (const float*)d_in[7];
    const float* q_b   = (const float*)d_in[8];
    const float* v_w   = (const float*)d_in[9];
    const float* v_b   = (const float*)d_in[10];
    const float* a_w   = (const float*)d_in[11];
    const float* a_b   = (const float*)d_in[12];
    const float* a_rel = (const float*)d_in[13];
    const float* m_rel = (const float*)d_in[14];
    const float* p_rel = (const float*)d_in[15];
    const float* skip  = (const float*)d_in[16];
    const int* esrc[4] = {(const int*)d_in[17], (const int*)d_in[19], (const int*)d_in[21], (const int*)d_in[23]};
    const int* edst[4] = {(const int*)d_in[18], (const int*)d_in[20], (const int*)d_in[22], (const int*)d_in[24]};
    const int* pos_src = (const int*)d_in[25];
    const int* pos_dst = (const int*)d_in[26];
    const int* neg_src = (const int*)d_in[27];
    const int* neg_dst = (const int*)d_in[28];

    float* ws   = (float*)d_ws;
    float* outp = (float*)d_out;
    int*   wi   = (int*)(ws + INT_OFF);

    // CSR build (once, all relations)
    hipMemsetAsync(wi + DEG_I, 0, 1200000L * sizeof(int), stream);   // deg + cur
    csr_count_all<<<(ETOT + 255) / 256, 256, 0, stream>>>(
        edst[0], edst[1], edst[2], edst[3], wi + DEG_I);
    const int nb = (NSEG + 1023) / 1024;   // 586
    scan1<<<nb, 256, 0, stream>>>(wi + DEG_I, wi + OFFS_I, wi + PART_I, NSEG);
    scan2<<<1, 256, 0, stream>>>(wi + PART_I, nb);
    scan3<<<(NSEG + 255) / 256, 256, 0, stream>>>(wi + OFFS_I, wi + PART_I, NSEG, ETOT);
    csr_fill_all<<<(ETOT + 255) / 256, 256, 0, stream>>>(
        esrc[0], edst[0], esrc[1], edst[1], esrc[2], edst[2], esrc[3], edst[3],
        wi + OFFS_I, wi + CUR_I, wi + CSRC_I);

    fuse_weights<<<4, 256, 0, stream>>>(k_w, k_b, v_w, v_b, a_rel, m_rel, ws + WF_OFF);

    const float* xin[3] = {xq, xa, xk};
    const int  cnt[3]  = {NQn, NAn, NKn};
    const long noff[3] = {0, NQn, NQn + NAn};

    // xs = relu(x @ lin_w + lin_b)
    for (int t = 0; t < 3; ++t)
        node_gemm<128, false, true, false><<<(cnt[t] + 63) / 64, 256, 0, stream>>>(
            xin[t], lin_w + (long)t * 128 * 64, lin_b + t * 64,
            ws + XS_OFF + noff[t] * 64, cnt[t], nullptr, nullptr);

    // q = xs @ q_w + q_b
    for (int t = 0; t < 3; ++t)
        node_gemm<64, false, false, false><<<(cnt[t] + 63) / 64, 256, 0, stream>>>(
            ws + XS_OFF + noff[t] * 64, q_w + (long)t * 64 * 64, q_b + t * 64,
            ws + Q_OFF + noff[t] * 64, cnt[t], nullptr, nullptr);

    const int  stt[4]   = {2, 0, 0, 1};
    const int  dtt[4]   = {0, 2, 1, 0};
    const long segb[4]  = {0, 100000, 300000, 500000};
    const float scale   = 0.17677669529663687f;   // 1/sqrt(32)
    unsigned short* kvb = (unsigned short*)(ws + KV_OFF);

    for (int r = 0; r < 4; ++r) {
        const int st = stt[r], dt = dtt[r];
        const int ndst = cnt[dt];

        kv_gemm<<<(cnt[st] + 63) / 64, 256, 0, stream>>>(
            ws + XS_OFF + noff[st] * 64, ws + WF_OFF + (long)r * 8320,
            ws + WF_OFF + (long)r * 8320 + 8192, kvb, cnt[st]);

        if (r == 3)
            attn_fused<true><<<(ndst + 3) / 4, 256, 0, stream>>>(
                wi + OFFS_I + segb[r], wi + CSRC_I, ws + Q_OFF + noff[dt] * 64,
                kvb, p_rel + r * 2, scale, ws + OUT_OFF + noff[dt] * 64, ndst);
        else
            attn_fused<false><<<(ndst + 3) / 4, 256, 0, stream>>>(
                wi + OFFS_I + segb[r], wi + CSRC_I, ws + Q_OFF + noff[dt] * 64,
                kvb, p_rel + r * 2, scale, ws + OUT_OFF + noff[dt] * 64, ndst);
    }

    // z = beta * (gelu(out) @ a_w + a_b) + (1-beta) * xs   -> straight into d_out
    const long zoff[3] = {200000L, 200000L + 6400000L, 200000L + 6400000L + 12800000L};
    for (int t = 0; t < 3; ++t)
        node_gemm<64, true, false, true><<<(cnt[t] + 63) / 64, 256, 0, stream>>>(
            ws + OUT_OFF + noff[t] * 64, a_w + (long)t * 64 * 64, a_b + t * 64,
            outp + zoff[t], cnt[t], ws + XS_OFF + noff[t] * 64, skip + t);

    pred_kernel<<<(EPc * 8 + 255) / 256, 256, 0, stream>>>(
        pos_src, pos_dst, EPc, outp + 200000, outp + 6600000, outp);
    pred_kernel<<<(ENc * 8 + 255) / 256, 256, 0, stream>>>(
        neg_src, neg_dst, ENc, outp + 200000, outp + 6600000, outp + EPc);
}

// Round 4
// 1149.901 us; speedup vs baseline: 2.8640x; 1.2209x over previous
//
#include <hip/hip_runtime.h>
#include <math.h>

namespace {

constexpr int NQn = 100000, NAn = 200000, NKn = 200000;
constexpr int EPc = 100000, ENc = 100000;
constexpr int ETOT = 2400000, NSEG = 600000;

// ---- workspace layout (float element offsets) ----
constexpr long XS_OFF  = 0;             // 32,000,000 (500k x 64 fp32)
constexpr long OUT_OFF = 32000000;      // 32,000,000 (500k x 64 fp32)
constexpr long QBF_OFF = 64000000;      // 16,000,000 floats = 32M bf16 (500k x 64)
constexpr long KV_OFF  = 80000000;      // 38,404,096 floats = 600064 rows x 128 bf16
constexpr long WF_OFF  = 118500000;     // 4*8320 fused interleaved rel weights
constexpr long INT_OFF = 118600000;     // int region below
// int offsets within (int*)(ws + INT_OFF):
constexpr long DEG_I  = 0;          // 600,000
constexpr long CUR_I  = 600000;     // 600,000
constexpr long OFFS_I = 1200000;    // 600,064
constexpr long PART_I = 1800064;    // 1,024
constexpr long CSRC_I = 1801088;    // 2,400,000
// end ~119.7M floats = 479 MB

// padded kv row bases per relation (starts multiple of 64)
__constant__ long c_rbase[4] = {0, 200000, 300032, 400064};

__device__ inline float gelu_f(float x) {
    return 0.5f * x * (1.0f + erff(x * 0.7071067811865475f));
}
__device__ inline float bf2f(unsigned short u) {
    return __uint_as_float(((unsigned)u) << 16);
}
__device__ inline unsigned short f2bf(float f) {
    unsigned u = __float_as_uint(f);
    return (unsigned short)((u + 0x7fffu + ((u >> 16) & 1u)) >> 16);
}

// block -> node-type mapping: type block counts {1563, 3125, 3125}
__device__ inline void type_of_block(int b, int& t, int& n0) {
    if (b < 1563)      { t = 0; n0 = b * 64; }
    else if (b < 4688) { t = 1; n0 = (b - 1563) * 64; }
    else               { t = 2; n0 = (b - 4688) * 64; }
}

// ---- fused interleaved relation weights: col c: i=c>>1 (out dim), which=c&1 (k/v)
__global__ void fuse_weights(const float* __restrict__ kw, const float* __restrict__ kb,
                             const float* __restrict__ vw, const float* __restrict__ vb,
                             const float* __restrict__ a_rel, const float* __restrict__ m_rel,
                             float* __restrict__ wf)
{
    const int r = blockIdx.x;
    const int st_tab[4] = {2, 0, 0, 1};
    const int st = st_tab[r];
    float* out = wf + (long)r * 8320;
    const int tid = threadIdx.x;
    for (int idx = tid; idx < 8192; idx += 256) {
        int d = idx >> 7, c = idx & 127;
        int i = c >> 1, which = c & 1;
        int h = i >> 5, e = i & 31;
        const float* w   = (which ? vw : kw) + st * 4096;
        const float* rel = (which ? m_rel : a_rel) + r * 2048;
        float s = 0.f;
        #pragma unroll
        for (int c32 = 0; c32 < 32; ++c32)
            s += w[d * 64 + h * 32 + c32] * rel[h * 1024 + c32 * 32 + e];
        out[idx] = s;
    }
    for (int idx = tid; idx < 128; idx += 256) {
        int i = idx >> 1, which = idx & 1;
        int h = i >> 5, e = i & 31;
        const float* b   = (which ? vb : kb) + st * 64;
        const float* rel = (which ? m_rel : a_rel) + r * 2048;
        float s = 0.f;
        #pragma unroll
        for (int c32 = 0; c32 < 32; ++c32)
            s += b[h * 32 + c32] * rel[h * 1024 + c32 * 32 + e];
        out[8192 + idx] = s;
    }
}

// ---- lin: xs = relu(x @ lin_w + lin_b), all 3 types in one launch ----
__global__ void __launch_bounds__(256)
lin_all(const float* __restrict__ xq, const float* __restrict__ xa,
        const float* __restrict__ xk, const float* __restrict__ lin_w,
        const float* __restrict__ lin_b, float* __restrict__ xs)
{
    __shared__ float ldsW[128 * 64];
    __shared__ float ldsX[128 * 64];
    int t, n0;
    type_of_block(blockIdx.x, t, n0);
    const int cnt[3] = {NQn, NAn, NKn};
    const long noff[3] = {0, NQn, NQn + NAn};
    const float* X = (t == 0) ? xq : (t == 1) ? xa : xk;
    const float* W = lin_w + (long)t * 8192;
    const int n = cnt[t];
    const int tid = threadIdx.x;

    for (int idx = tid; idx < 8192; idx += 256) ldsW[idx] = W[idx];
    for (int idx = tid; idx < 8192; idx += 256) {
        int r = idx >> 7, c = idx & 127;
        int node = n0 + r; if (node > n - 1) node = n - 1;
        ldsX[c * 64 + (r ^ (c & 31))] = X[(long)node * 128 + c];
    }
    __syncthreads();

    const int j = tid & 15;
    const int i = tid >> 4;
    float acc[4][4] = {};
    #pragma unroll 4
    for (int d = 0; d < 128; ++d) {
        float4 wv = *(const float4*)&ldsW[d * 64 + j * 4];
        float xv[4];
        #pragma unroll
        for (int k = 0; k < 4; ++k) xv[k] = ldsX[d * 64 + ((i * 4 + k) ^ (d & 31))];
        #pragma unroll
        for (int k = 0; k < 4; ++k) {
            acc[k][0] += xv[k] * wv.x; acc[k][1] += xv[k] * wv.y;
            acc[k][2] += xv[k] * wv.z; acc[k][3] += xv[k] * wv.w;
        }
    }
    const float4 bv = *(const float4*)&lin_b[t * 64 + j * 4];
    #pragma unroll
    for (int k = 0; k < 4; ++k) {
        int node = n0 + i * 4 + k;
        if (node < n) {
            float4 o;
            o.x = fmaxf(acc[k][0] + bv.x, 0.f); o.y = fmaxf(acc[k][1] + bv.y, 0.f);
            o.z = fmaxf(acc[k][2] + bv.z, 0.f); o.w = fmaxf(acc[k][3] + bv.w, 0.f);
            *(float4*)&xs[(noff[t] + node) * 64 + j * 4] = o;
        }
    }
}

// ---- proj: q (bf16) for all 500k nodes + kv (bf16) for all 4 relations ----
// blocks [0,7813): q path; [7813, 7813+9376): kv path
__global__ void __launch_bounds__(256)
proj_all(const float* __restrict__ xs, const float* __restrict__ q_w,
         const float* __restrict__ q_b, const float* __restrict__ wf,
         unsigned short* __restrict__ qbf, unsigned short* __restrict__ kvb)
{
    __shared__ float ldsW[8192];
    __shared__ float ldsX[4096];
    const int tid = threadIdx.x;
    const int cnt[3] = {NQn, NAn, NKn};
    const long noff[3] = {0, NQn, NQn + NAn};

    if (blockIdx.x < 7813) {
        // ---- q path: 64 nodes, 64 cols
        int t, n0;
        type_of_block(blockIdx.x, t, n0);
        const int n = cnt[t];
        const float* W = q_w + (long)t * 4096;

        for (int idx = tid; idx < 4096; idx += 256) ldsW[idx] = W[idx];
        for (int idx = tid; idx < 4096; idx += 256) {
            int r = idx >> 6, c = idx & 63;
            int node = n0 + r; if (node > n - 1) node = n - 1;
            ldsX[c * 64 + (r ^ (c & 31))] = xs[(noff[t] + node) * 64 + c];
        }
        __syncthreads();

        const int j = tid & 15;
        const int i = tid >> 4;
        float acc[4][4] = {};
        #pragma unroll 4
        for (int d = 0; d < 64; ++d) {
            float4 wv = *(const float4*)&ldsW[d * 64 + j * 4];
            float xv[4];
            #pragma unroll
            for (int k = 0; k < 4; ++k) xv[k] = ldsX[d * 64 + ((i * 4 + k) ^ (d & 31))];
            #pragma unroll
            for (int k = 0; k < 4; ++k) {
                acc[k][0] += xv[k] * wv.x; acc[k][1] += xv[k] * wv.y;
                acc[k][2] += xv[k] * wv.z; acc[k][3] += xv[k] * wv.w;
            }
        }
        const float4 bv = *(const float4*)&q_b[t * 64 + j * 4];
        #pragma unroll
        for (int k = 0; k < 4; ++k) {
            int node = n0 + i * 4 + k;
            if (node < n) {
                ushort4 o;
                o.x = f2bf(acc[k][0] + bv.x); o.y = f2bf(acc[k][1] + bv.y);
                o.z = f2bf(acc[k][2] + bv.z); o.w = f2bf(acc[k][3] + bv.w);
                *(ushort4*)&qbf[(noff[t] + node) * 64 + j * 4] = o;
            }
        }
    } else {
        // ---- kv path: 64 rows, 128 cols; relation block counts {3125,1563,1563,3125}
        int kb = blockIdx.x - 7813;
        int r, lb;
        if (kb < 3125)      { r = 0; lb = kb; }
        else if (kb < 4688) { r = 1; lb = kb - 3125; }
        else if (kb < 6251) { r = 2; lb = kb - 4688; }
        else                { r = 3; lb = kb - 6251; }
        const int stt[4] = {2, 0, 0, 1};
        const int st = stt[r];
        const int n0 = lb * 64;
        const int n = cnt[st];
        const float* W = wf + (long)r * 8320;
        const long rb = c_rbase[r];

        for (int idx = tid; idx < 8192; idx += 256) ldsW[idx] = W[idx];
        for (int idx = tid; idx < 4096; idx += 256) {
            int rr = idx >> 6, c = idx & 63;
            int node = n0 + rr; if (node > n - 1) node = n - 1;
            ldsX[c * 64 + (rr ^ (c & 31))] = xs[(noff[st] + node) * 64 + c];
        }
        __syncthreads();

        const int j = tid & 31;   // 32 col-groups x 4
        const int i = tid >> 5;   // 8 node-groups x 8
        float acc[8][4] = {};
        #pragma unroll 4
        for (int d = 0; d < 64; ++d) {
            float4 wv = *(const float4*)&ldsW[d * 128 + j * 4];
            #pragma unroll
            for (int k = 0; k < 8; ++k) {
                float xv = ldsX[d * 64 + ((i * 8 + k) ^ (d & 31))];
                acc[k][0] += xv * wv.x; acc[k][1] += xv * wv.y;
                acc[k][2] += xv * wv.z; acc[k][3] += xv * wv.w;
            }
        }
        const float4 bv = *(const float4*)&wf[(long)r * 8320 + 8192 + j * 4];
        #pragma unroll
        for (int k = 0; k < 8; ++k) {
            int node = n0 + i * 8 + k;
            if (node < n) {
                ushort4 o;
                o.x = f2bf(acc[k][0] + bv.x); o.y = f2bf(acc[k][1] + bv.y);
                o.z = f2bf(acc[k][2] + bv.z); o.w = f2bf(acc[k][3] + bv.w);
                *(ushort4*)&kvb[(rb + node) * 128 + j * 4] = o;
            }
        }
    }
}

// ---- CSR build, all 4 relations at once ------------------------------------
__global__ void csr_count_all(const int* __restrict__ d0, const int* __restrict__ d1,
                              const int* __restrict__ d2, const int* __restrict__ d3,
                              int* __restrict__ deg)
{
    int gid = blockIdx.x * 256 + threadIdx.x;
    if (gid < 800000)       atomicAdd(&deg[d0[gid]], 1);
    else if (gid < 1600000) atomicAdd(&deg[100000 + d1[gid - 800000]], 1);
    else if (gid < 2000000) atomicAdd(&deg[300000 + d2[gid - 1600000]], 1);
    else if (gid < 2400000) atomicAdd(&deg[500000 + d3[gid - 2000000]], 1);
}

__global__ void csr_fill_all(const int* __restrict__ s0, const int* __restrict__ d0,
                             const int* __restrict__ s1, const int* __restrict__ d1,
                             const int* __restrict__ s2, const int* __restrict__ d2,
                             const int* __restrict__ s3, const int* __restrict__ d3,
                             const int* __restrict__ off, int* __restrict__ cur,
                             int* __restrict__ csrc)
{
    int gid = blockIdx.x * 256 + threadIdx.x;
    int seg, s;
    if (gid < 800000)       { seg = d0[gid];                    s = s0[gid]; }
    else if (gid < 1600000) { seg = 100000 + d1[gid - 800000];  s = s1[gid - 800000]; }
    else if (gid < 2000000) { seg = 300000 + d2[gid - 1600000]; s = s2[gid - 1600000]; }
    else if (gid < 2400000) { seg = 500000 + d3[gid - 2000000]; s = s3[gid - 2000000]; }
    else return;
    int slot = off[seg] + atomicAdd(&cur[seg], 1);
    csrc[slot] = s;
}

__global__ void scan1(const int* __restrict__ in, int* __restrict__ out,
                      int* __restrict__ part, int n)
{
    __shared__ int lds[256];
    const int tid = threadIdx.x;
    const int base = blockIdx.x * 1024 + tid * 4;
    int v[4];
    #pragma unroll
    for (int k = 0; k < 4; ++k) v[k] = (base + k < n) ? in[base + k] : 0;
    int tsum = v[0] + v[1] + v[2] + v[3];
    lds[tid] = tsum;
    __syncthreads();
    for (int off = 1; off < 256; off <<= 1) {
        int t = (tid >= off) ? lds[tid - off] : 0;
        __syncthreads();
        lds[tid] += t;
        __syncthreads();
    }
    int excl = lds[tid] - tsum;
    #pragma unroll
    for (int k = 0; k < 4; ++k) {
        if (base + k < n) out[base + k] = excl;
        excl += v[k];
    }
    if (tid == 255) part[blockIdx.x] = lds[255];
}

__global__ void scan2(int* __restrict__ part, int nb)   // nb <= 1024
{
    __shared__ int lds[256];
    const int tid = threadIdx.x;
    const int base = tid * 4;
    int v[4];
    #pragma unroll
    for (int k = 0; k < 4; ++k) v[k] = (base + k < nb) ? part[base + k] : 0;
    int tsum = v[0] + v[1] + v[2] + v[3];
    lds[tid] = tsum;
    __syncthreads();
    for (int off = 1; off < 256; off <<= 1) {
        int t = (tid >= off) ? lds[tid - off] : 0;
        __syncthreads();
        lds[tid] += t;
        __syncthreads();
    }
    int excl = lds[tid] - tsum;
    #pragma unroll
    for (int k = 0; k < 4; ++k) {
        if (base + k < nb) part[base + k] = excl;
        excl += v[k];
    }
}

__global__ void scan3(int* __restrict__ off, const int* __restrict__ part, int n, int E)
{
    int i = blockIdx.x * 256 + threadIdx.x;
    if (i < n) off[i] += part[i >> 10];
    if (i == 0) off[n] = E;
}

// ---- merged fused attention: one wave per dst node, all relations ----------
__device__ inline float attn_seg(const int* __restrict__ csrc, int begin, int end,
                                 const unsigned short* __restrict__ kv, long kvbase,
                                 float qv, float pscale, int lane)
{
    float m = -INFINITY, ssum = 0.f, acc = 0.f;
    for (int t = begin; t < end; t += 4) {
        int i1 = t + 1 < end ? t + 1 : end - 1;
        int i2 = t + 2 < end ? t + 2 : end - 1;
        int i3 = t + 3 < end ? t + 3 : end - 1;
        int s0 = csrc[t], s1 = csrc[i1], s2 = csrc[i2], s3 = csrc[i3];
        ushort2 c0 = ((const ushort2*)(kv + (kvbase + s0) * 128))[lane];
        ushort2 c1 = ((const ushort2*)(kv + (kvbase + s1) * 128))[lane];
        ushort2 c2 = ((const ushort2*)(kv + (kvbase + s2) * 128))[lane];
        ushort2 c3 = ((const ushort2*)(kv + (kvbase + s3) * 128))[lane];
        float p0 = qv * bf2f(c0.x), p1 = qv * bf2f(c1.x);
        float p2 = qv * bf2f(c2.x), p3 = qv * bf2f(c3.x);
        // 4 interleaved butterfly reduces (independent chains -> ILP)
        p0 += __shfl_xor(p0, 1);  p1 += __shfl_xor(p1, 1);
        p2 += __shfl_xor(p2, 1);  p3 += __shfl_xor(p3, 1);
        p0 += __shfl_xor(p0, 2);  p1 += __shfl_xor(p1, 2);
        p2 += __shfl_xor(p2, 2);  p3 += __shfl_xor(p3, 2);
        p0 += __shfl_xor(p0, 4);  p1 += __shfl_xor(p1, 4);
        p2 += __shfl_xor(p2, 4);  p3 += __shfl_xor(p3, 4);
        p0 += __shfl_xor(p0, 8);  p1 += __shfl_xor(p1, 8);
        p2 += __shfl_xor(p2, 8);  p3 += __shfl_xor(p3, 8);
        p0 += __shfl_xor(p0, 16); p1 += __shfl_xor(p1, 16);
        p2 += __shfl_xor(p2, 16); p3 += __shfl_xor(p3, 16);
        float a0 = p0 * pscale;
        float a1 = (t + 1 < end) ? p1 * pscale : -INFINITY;
        float a2 = (t + 2 < end) ? p2 * pscale : -INFINITY;
        float a3 = (t + 3 < end) ? p3 * pscale : -INFINITY;
        float tm = fmaxf(fmaxf(a0, a1), fmaxf(a2, a3));
        float mn = fmaxf(m, tm);
        float corr = __expf(m - mn);
        float w0 = __expf(a0 - mn), w1 = __expf(a1 - mn);
        float w2 = __expf(a2 - mn), w3 = __expf(a3 - mn);
        ssum = ssum * corr + ((w0 + w1) + (w2 + w3));
        acc = acc * corr + (w0 * bf2f(c0.y) + w1 * bf2f(c1.y))
                         + (w2 * bf2f(c2.y) + w3 * bf2f(c3.y));
        m = mn;
    }
    return acc / (ssum + 1e-16f);
}

__global__ void __launch_bounds__(256)
attn_all(const int* __restrict__ off, const int* __restrict__ csrc,
         const unsigned short* __restrict__ qbf, const unsigned short* __restrict__ kv,
         const float* __restrict__ prel, float scale, float* __restrict__ out)
{
    const int wid = blockIdx.x * 4 + (threadIdx.x >> 6);
    const int lane = threadIdx.x & 63;
    if (wid >= 500000) return;
    const int h = lane >> 5;

    if (wid < 100000) {
        // question node: r0 (k->q) + r3 (a->q)
        const long row = wid;
        const float qv = bf2f(qbf[row * 64 + lane]);
        float r0 = attn_seg(csrc, off[wid], off[wid + 1], kv, c_rbase[0],
                            qv, prel[0 * 2 + h] * scale, lane);
        float r3 = attn_seg(csrc, off[500000 + wid], off[500000 + wid + 1], kv, c_rbase[3],
                            qv, prel[3 * 2 + h] * scale, lane);
        out[row * 64 + lane] = r0 + r3;
    } else if (wid < 300000) {
        // knowledge node: r1 (q->k)
        const int kk = wid - 100000;
        const long row = 300000 + kk;
        const float qv = bf2f(qbf[row * 64 + lane]);
        float r1 = attn_seg(csrc, off[100000 + kk], off[100000 + kk + 1], kv, c_rbase[1],
                            qv, prel[1 * 2 + h] * scale, lane);
        out[row * 64 + lane] = r1;
    } else {
        // answer node: r2 (q->a)
        const int aa = wid - 300000;
        const long row = 100000 + aa;
        const float qv = bf2f(qbf[row * 64 + lane]);
        float r2 = attn_seg(csrc, off[300000 + aa], off[300000 + aa + 1], kv, c_rbase[2],
                            qv, prel[2 * 2 + h] * scale, lane);
        out[row * 64 + lane] = r2;
    }
}

// ---- head: z = beta*(gelu(out) @ a_w + a_b) + (1-beta)*xs, all types --------
__global__ void __launch_bounds__(256)
head_all(const float* __restrict__ outa, const float* __restrict__ xs,
         const float* __restrict__ a_w, const float* __restrict__ a_b,
         const float* __restrict__ skip, float* __restrict__ z)
{
    __shared__ float ldsW[4096];
    __shared__ float ldsX[4096];
    int t, n0;
    type_of_block(blockIdx.x, t, n0);
    const int cnt[3] = {NQn, NAn, NKn};
    const long noff[3] = {0, NQn, NQn + NAn};
    const long zoff[3] = {200000L, 200000L + 6400000L, 200000L + 6400000L + 12800000L};
    const int n = cnt[t];
    const float* W = a_w + (long)t * 4096;
    const int tid = threadIdx.x;

    for (int idx = tid; idx < 4096; idx += 256) ldsW[idx] = W[idx];
    for (int idx = tid; idx < 4096; idx += 256) {
        int r = idx >> 6, c = idx & 63;
        int node = n0 + r; if (node > n - 1) node = n - 1;
        ldsX[c * 64 + (r ^ (c & 31))] = gelu_f(outa[(noff[t] + node) * 64 + c]);
    }
    __syncthreads();

    const int j = tid & 15;
    const int i = tid >> 4;
    float acc[4][4] = {};
    #pragma unroll 4
    for (int d = 0; d < 64; ++d) {
        float4 wv = *(const float4*)&ldsW[d * 64 + j * 4];
        float xv[4];
        #pragma unroll
        for (int k = 0; k < 4; ++k) xv[k] = ldsX[d * 64 + ((i * 4 + k) ^ (d & 31))];
        #pragma unroll
        for (int k = 0; k < 4; ++k) {
            acc[k][0] += xv[k] * wv.x; acc[k][1] += xv[k] * wv.y;
            acc[k][2] += xv[k] * wv.z; acc[k][3] += xv[k] * wv.w;
        }
    }
    const float4 bv = *(const float4*)&a_b[t * 64 + j * 4];
    const float beta = 1.f / (1.f + expf(-skip[t]));
    #pragma unroll
    for (int k = 0; k < 4; ++k) {
        int node = n0 + i * 4 + k;
        if (node < n) {
            float4 rv = *(const float4*)&xs[(noff[t] + node) * 64 + j * 4];
            float4 o;
            o.x = beta * (acc[k][0] + bv.x) + (1.f - beta) * rv.x;
            o.y = beta * (acc[k][1] + bv.y) + (1.f - beta) * rv.y;
            o.z = beta * (acc[k][2] + bv.z) + (1.f - beta) * rv.z;
            o.w = beta * (acc[k][3] + bv.w) + (1.f - beta) * rv.w;
            *(float4*)&z[zoff[t] + (long)node * 64 + j * 4] = o;
        }
    }
}

// ---- link prediction: pos + neg in one launch ------------------------------
__global__ void pred_all(const int* __restrict__ psrc, const int* __restrict__ pdst,
                         const int* __restrict__ nsrc, const int* __restrict__ ndst,
                         const float* __restrict__ zq, const float* __restrict__ za,
                         float* __restrict__ out)
{
    int t = blockIdx.x * 256 + threadIdx.x;
    int g = t >> 3, lane = t & 7;
    if (g >= EPc + ENc) return;
    int s, d, oi;
    if (g < EPc) { s = psrc[g]; d = pdst[g]; oi = g; }
    else         { int gg = g - EPc; s = nsrc[gg]; d = ndst[gg]; oi = g; }
    const float4* zs = (const float4*)&zq[(long)s * 64 + lane * 8];
    const float4* zd = (const float4*)&za[(long)d * 64 + lane * 8];
    float4 a0 = zs[0], a1 = zs[1], b0 = zd[0], b1 = zd[1];
    float p = a0.x * b0.x + a0.y * b0.y + a0.z * b0.z + a0.w * b0.w
            + a1.x * b1.x + a1.y * b1.y + a1.z * b1.z + a1.w * b1.w;
    p += __shfl_xor(p, 1);
    p += __shfl_xor(p, 2);
    p += __shfl_xor(p, 4);
    if (lane == 0) out[oi] = 1.f / (1.f + expf(-p));
}

} // namespace

extern "C" void kernel_launch(void* const* d_in, const int* in_sizes, int n_in,
                              void* d_out, int out_size, void* d_ws, size_t ws_size,
                              hipStream_t stream)
{
    const float* xq    = (const float*)d_in[0];
    const float* xa    = (const float*)d_in[1];
    const float* xk    = (const float*)d_in[2];
    const float* lin_w = (const float*)d_in[3];
    const float* lin_b = (const float*)d_in[4];
    const float* k_w   = (const float*)d_in[5];
    const float* k_b   = (const float*)d_in[6];
    const float* q_w   = (const float*)d_in[7];
    const float* q_b   = (const float*)d_in[8];
    const float* v_w   = (const float*)d_in[9];
    const float* v_b   = (const float*)d_in[10];
    const float* a_w   = (const float*)d_in[11];
    const float* a_b   = (const float*)d_in[12];
    const float* a_rel = (const float*)d_in[13];
    const float* m_rel = (const float*)d_in[14];
    const float* p_rel = (const float*)d_in[15];
    const float* skip  = (const float*)d_in[16];
    const int* esrc[4] = {(const int*)d_in[17], (const int*)d_in[19], (const int*)d_in[21], (const int*)d_in[23]};
    const int* edst[4] = {(const int*)d_in[18], (const int*)d_in[20], (const int*)d_in[22], (const int*)d_in[24]};
    const int* pos_src = (const int*)d_in[25];
    const int* pos_dst = (const int*)d_in[26];
    const int* neg_src = (const int*)d_in[27];
    const int* neg_dst = (const int*)d_in[28];

    float* ws   = (float*)d_ws;
    float* outp = (float*)d_out;
    int*   wi   = (int*)(ws + INT_OFF);
    unsigned short* qbf = (unsigned short*)(ws + QBF_OFF);
    unsigned short* kvb = (unsigned short*)(ws + KV_OFF);

    // CSR build (once, all relations)
    hipMemsetAsync(wi + DEG_I, 0, 1200000L * sizeof(int), stream);
    csr_count_all<<<(ETOT + 255) / 256, 256, 0, stream>>>(
        edst[0], edst[1], edst[2], edst[3], wi + DEG_I);
    const int nb = (NSEG + 1023) / 1024;   // 586
    scan1<<<nb, 256, 0, stream>>>(wi + DEG_I, wi + OFFS_I, wi + PART_I, NSEG);
    scan2<<<1, 256, 0, stream>>>(wi + PART_I, nb);
    scan3<<<(NSEG + 255) / 256, 256, 0, stream>>>(wi + OFFS_I, wi + PART_I, NSEG, ETOT);
    csr_fill_all<<<(ETOT + 255) / 256, 256, 0, stream>>>(
        esrc[0], edst[0], esrc[1], edst[1], esrc[2], edst[2], esrc[3], edst[3],
        wi + OFFS_I, wi + CUR_I, wi + CSRC_I);

    fuse_weights<<<4, 256, 0, stream>>>(k_w, k_b, v_w, v_b, a_rel, m_rel, ws + WF_OFF);

    // xs = relu(x @ lin_w + lin_b)   (one launch, 7813 blocks)
    lin_all<<<7813, 256, 0, stream>>>(xq, xa, xk, lin_w, lin_b, ws + XS_OFF);

    // q (bf16) + kv (bf16, 4 relations)   (one launch, 7813 + 9376 blocks)
    proj_all<<<7813 + 9376, 256, 0, stream>>>(ws + XS_OFF, q_w, q_b, ws + WF_OFF, qbf, kvb);

    // merged attention over all 500k destination nodes
    const float scale = 0.17677669529663687f;   // 1/sqrt(32)
    attn_all<<<125000, 256, 0, stream>>>(wi + OFFS_I, wi + CSRC_I, qbf, kvb,
                                         p_rel, scale, ws + OUT_OFF);

    // output head (one launch)
    head_all<<<7813, 256, 0, stream>>>(ws + OUT_OFF, ws + XS_OFF, a_w, a_b, skip, outp);

    // link predictions (one launch)
    pred_all<<<(200000 * 8 + 255) / 256, 256, 0, stream>>>(
        pos_src, pos_dst, neg_src, neg_dst,
        outp + 200000, outp + 6600000, outp);
}

// Round 5
// 860.977 us; speedup vs baseline: 3.8251x; 1.3356x over previous
//
#include <hip/hip_runtime.h>
#include <math.h>

namespace {

constexpr int NQn = 100000, NAn = 200000, NKn = 200000;
constexpr int EPc = 100000, ENc = 100000;
constexpr int ETOT = 2400000, NSEG = 600000;

// ---- workspace layout (float element offsets) ----
constexpr long XSB_OFF = 0;             // 16,000,000 floats = 32M bf16 xs
constexpr long OUT_OFF = 16000000;      // 32,000,000 fp32 attn accum
constexpr long QBF_OFF = 48000000;      // 16,000,000 floats = 32M bf16 q
constexpr long KV_OFF  = 64000000;      // 38,404,096 floats-worth of bf16 kv (600064 x 128)
constexpr long WTB_OFF = 102500000;     // bf16 transposed weights (81,920 ushorts)
constexpr long WFB_OFF = 102550000;     // fp32 fused kv bias (512 floats)
constexpr long INT_OFF = 102560000;     // int region
// int offsets within (int*)(ws + INT_OFF):
constexpr long DEG_I  = 0;
constexpr long CUR_I  = 600000;
constexpr long OFFS_I = 1200000;
constexpr long PART_I = 1800064;
constexpr long CSRC_I = 1801088;

// wtb ushort offsets
constexpr int LINT_U = 0;        // 3 x 64 x 128
constexpr int QT_U   = 24576;    // 3 x 64 x 64
constexpr int AT_U   = 36864;    // 3 x 64 x 64
constexpr int WFT_U  = 49152;    // 4 x 128 x 64

__constant__ long c_rbase[4] = {0, 200000, 300032, 400064};

typedef __attribute__((ext_vector_type(8))) short bf16x8;
typedef __attribute__((ext_vector_type(4))) float f32x4;

__device__ inline f32x4 mfma16(bf16x8 a, bf16x8 b, f32x4 c) {
    return __builtin_amdgcn_mfma_f32_16x16x32_bf16(a, b, c, 0, 0, 0);
}

__device__ inline float gelu_f(float x) {
    return 0.5f * x * (1.0f + erff(x * 0.7071067811865475f));
}
__device__ inline float bf2f(unsigned short u) {
    return __uint_as_float(((unsigned)u) << 16);
}
__device__ inline unsigned short f2bf(float f) {
    unsigned u = __float_as_uint(f);
    return (unsigned short)((u + 0x7fffu + ((u >> 16) & 1u)) >> 16);
}

// block -> node-type mapping for 128-row tiles: counts {782, 1563, 1563}
__device__ inline void type_of_block128(int b, int& t, int& n0) {
    if (b < 782)       { t = 0; n0 = b * 128; }
    else if (b < 2345) { t = 1; n0 = (b - 782) * 128; }
    else               { t = 2; n0 = (b - 2345) * 128; }
}

// ---- staging helpers (XOR-swizzled LDS, 16B chunks) ----
template<int K>
__device__ inline void stage_bf16(unsigned short* lds, const unsigned short* src,
                                  int n0, int n, int tid)
{
    constexpr int CPR = K / 8;
    for (int c = tid; c < 128 * CPR; c += 256) {
        int row = c / CPR, kc = c % CPR;
        int node = n0 + row; if (node > n - 1) node = n - 1;
        uint4 v = *(const uint4*)&src[(long)node * K + kc * 8];
        int byte = (row * K + kc * 8) * 2;
        *(uint4*)((char*)lds + (byte ^ ((row & 7) << 4))) = v;
    }
}

template<int K, bool GELU>
__device__ inline void stage_f32(unsigned short* lds, const float* src,
                                 int n0, int n, int tid)
{
    constexpr int CPR = K / 8;
    for (int c = tid; c < 128 * CPR; c += 256) {
        int row = c / CPR, kc = c % CPR;
        int node = n0 + row; if (node > n - 1) node = n - 1;
        const float* sp = &src[(long)node * K + kc * 8];
        float4 f0 = *(const float4*)sp, f1 = *(const float4*)(sp + 4);
        if (GELU) {
            f0.x = gelu_f(f0.x); f0.y = gelu_f(f0.y);
            f0.z = gelu_f(f0.z); f0.w = gelu_f(f0.w);
            f1.x = gelu_f(f1.x); f1.y = gelu_f(f1.y);
            f1.z = gelu_f(f1.z); f1.w = gelu_f(f1.w);
        }
        uint4 v;
        v.x = (unsigned)f2bf(f0.x) | ((unsigned)f2bf(f0.y) << 16);
        v.y = (unsigned)f2bf(f0.z) | ((unsigned)f2bf(f0.w) << 16);
        v.z = (unsigned)f2bf(f1.x) | ((unsigned)f2bf(f1.y) << 16);
        v.w = (unsigned)f2bf(f1.z) | ((unsigned)f2bf(f1.w) << 16);
        int byte = (row * K + kc * 8) * 2;
        *(uint4*)((char*)lds + (byte ^ ((row & 7) << 4))) = v;
    }
}

template<int N, int K>
__device__ inline void stage_w(unsigned short* lds, const unsigned short* wt, int tid)
{
    constexpr int CPR = K / 8;
    for (int c = tid; c < N * CPR; c += 256) {
        int nr = c / CPR, kc = c % CPR;
        uint4 v = *(const uint4*)&wt[nr * K + kc * 8];
        int byte = (nr * K + kc * 8) * 2;
        *(uint4*)((char*)lds + (byte ^ ((nr & 7) << 4))) = v;
    }
}

// ---- MFMA core: wave w computes rows [w*32, w*32+32) x all N cols ----
template<int K, int NF>
__device__ inline void mfma_core(const unsigned short* ldsX, const unsigned short* ldsW,
                                 f32x4 (&acc)[2][NF], int lane, int w)
{
    const int lrow = lane & 15, lk = (lane >> 4) * 8;
    #pragma unroll
    for (int ks = 0; ks < K / 32; ++ks) {
        bf16x8 a[2], b[NF];
        #pragma unroll
        for (int mf = 0; mf < 2; ++mf) {
            int row = w * 32 + mf * 16 + lrow;
            int byte = (row * K + ks * 32 + lk) * 2;
            a[mf] = *(const bf16x8*)((const char*)ldsX + (byte ^ ((row & 7) << 4)));
        }
        #pragma unroll
        for (int nf = 0; nf < NF; ++nf) {
            int nr = nf * 16 + lrow;
            int byte = (nr * K + ks * 32 + lk) * 2;
            b[nf] = *(const bf16x8*)((const char*)ldsW + (byte ^ ((nr & 7) << 4)));
        }
        #pragma unroll
        for (int mf = 0; mf < 2; ++mf)
            #pragma unroll
            for (int nf = 0; nf < NF; ++nf)
                acc[mf][nf] = mfma16(a[mf], b[nf], acc[mf][nf]);
    }
}

// ---- weight prep: transpose + bf16 ----
__global__ void prep_w(const float* __restrict__ lin_w, const float* __restrict__ q_w,
                       const float* __restrict__ a_w, unsigned short* __restrict__ wtb)
{
    int i = blockIdx.x * 256 + threadIdx.x;
    if (i < 24576) {
        int t = i / 8192, rem = i % 8192, nn = rem >> 7, kk = rem & 127;
        wtb[LINT_U + i] = f2bf(lin_w[t * 8192 + kk * 64 + nn]);
    } else if (i < 36864) {
        int j = i - 24576;
        int t = j / 4096, rem = j % 4096, nn = rem >> 6, kk = rem & 63;
        wtb[QT_U + j] = f2bf(q_w[t * 4096 + kk * 64 + nn]);
    } else if (i < 49152) {
        int j = i - 36864;
        int t = j / 4096, rem = j % 4096, nn = rem >> 6, kk = rem & 63;
        wtb[AT_U + j] = f2bf(a_w[t * 4096 + kk * 64 + nn]);
    }
}

// ---- fused relation weights, transposed bf16: wfT[r][c(0..127)][d(0..63)] ----
__global__ void fuse_weights(const float* __restrict__ kw, const float* __restrict__ kb,
                             const float* __restrict__ vw, const float* __restrict__ vb,
                             const float* __restrict__ a_rel, const float* __restrict__ m_rel,
                             unsigned short* __restrict__ wtb, float* __restrict__ wfb)
{
    const int r = blockIdx.x;
    const int st_tab[4] = {2, 0, 0, 1};
    const int st = st_tab[r];
    const int tid = threadIdx.x;
    for (int idx = tid; idx < 8192; idx += 256) {
        int d = idx >> 7, c = idx & 127;
        int i = c >> 1, which = c & 1;
        int h = i >> 5, e = i & 31;
        const float* w   = (which ? vw : kw) + st * 4096;
        const float* rel = (which ? m_rel : a_rel) + r * 2048;
        float s = 0.f;
        #pragma unroll
        for (int c32 = 0; c32 < 32; ++c32)
            s += w[d * 64 + h * 32 + c32] * rel[h * 1024 + c32 * 32 + e];
        wtb[WFT_U + r * 8192 + c * 64 + d] = f2bf(s);
    }
    for (int idx = tid; idx < 128; idx += 256) {
        int i = idx >> 1, which = idx & 1;
        int h = i >> 5, e = i & 31;
        const float* b   = (which ? vb : kb) + st * 64;
        const float* rel = (which ? m_rel : a_rel) + r * 2048;
        float s = 0.f;
        #pragma unroll
        for (int c32 = 0; c32 < 32; ++c32)
            s += b[h * 32 + c32] * rel[h * 1024 + c32 * 32 + e];
        wfb[r * 128 + idx] = s;
    }
}

// ---- lin: xs_bf16 = relu(x @ lin_w + lin_b) ----
__global__ void __launch_bounds__(256)
lin_mfma(const float* __restrict__ xq, const float* __restrict__ xa,
         const float* __restrict__ xk, const unsigned short* __restrict__ wtb,
         const float* __restrict__ lin_b, unsigned short* __restrict__ xsb)
{
    __shared__ unsigned short ldsX[128 * 128];
    __shared__ unsigned short ldsW[64 * 128];
    int t, n0; type_of_block128(blockIdx.x, t, n0);
    const int cnt[3] = {NQn, NAn, NKn};
    const long noff[3] = {0, NQn, NQn + NAn};
    const float* X = (t == 0) ? xq : (t == 1) ? xa : xk;
    const int n = cnt[t];
    const int tid = threadIdx.x;

    stage_w<64, 128>(ldsW, wtb + LINT_U + t * 8192, tid);
    stage_f32<128, false>(ldsX, X, n0, n, tid);
    __syncthreads();

    const int w = tid >> 6, lane = tid & 63;
    f32x4 acc[2][4] = {};
    mfma_core<128, 4>(ldsX, ldsW, acc, lane, w);

    const int prow = (lane >> 4) * 4, pcol = lane & 15;
    #pragma unroll
    for (int mf = 0; mf < 2; ++mf)
      #pragma unroll
      for (int nf = 0; nf < 4; ++nf)
        #pragma unroll
        for (int i = 0; i < 4; ++i) {
            int node = n0 + w * 32 + mf * 16 + prow + i;
            if (node < n) {
                int col = nf * 16 + pcol;
                float v = fmaxf(acc[mf][nf][i] + lin_b[t * 64 + col], 0.f);
                xsb[(noff[t] + node) * 64 + col] = f2bf(v);
            }
        }
}

// ---- q: q_bf16 = xs @ q_w + q_b ----
__global__ void __launch_bounds__(256)
q_mfma(const unsigned short* __restrict__ xsb, const unsigned short* __restrict__ wtb,
       const float* __restrict__ q_b, unsigned short* __restrict__ qbf)
{
    __shared__ unsigned short ldsX[128 * 64];
    __shared__ unsigned short ldsW[64 * 64];
    int t, n0; type_of_block128(blockIdx.x, t, n0);
    const int cnt[3] = {NQn, NAn, NKn};
    const long noff[3] = {0, NQn, NQn + NAn};
    const int n = cnt[t];
    const int tid = threadIdx.x;

    stage_w<64, 64>(ldsW, wtb + QT_U + t * 4096, tid);
    stage_bf16<64>(ldsX, xsb + noff[t] * 64, n0, n, tid);
    __syncthreads();

    const int w = tid >> 6, lane = tid & 63;
    f32x4 acc[2][4] = {};
    mfma_core<64, 4>(ldsX, ldsW, acc, lane, w);

    const int prow = (lane >> 4) * 4, pcol = lane & 15;
    #pragma unroll
    for (int mf = 0; mf < 2; ++mf)
      #pragma unroll
      for (int nf = 0; nf < 4; ++nf)
        #pragma unroll
        for (int i = 0; i < 4; ++i) {
            int node = n0 + w * 32 + mf * 16 + prow + i;
            if (node < n) {
                int col = nf * 16 + pcol;
                qbf[(noff[t] + node) * 64 + col] = f2bf(acc[mf][nf][i] + q_b[t * 64 + col]);
            }
        }
}

// ---- kv: interleaved k/v bf16, 4 relations; blocks {1563, 782, 782, 1563} ----
__global__ void __launch_bounds__(256)
kv_mfma(const unsigned short* __restrict__ xsb, const unsigned short* __restrict__ wtb,
        const float* __restrict__ wfb, unsigned short* __restrict__ kvb)
{
    __shared__ unsigned short ldsX[128 * 64];
    __shared__ unsigned short ldsW[128 * 64];
    int kb = blockIdx.x, r, lb;
    if (kb < 1563)      { r = 0; lb = kb; }
    else if (kb < 2345) { r = 1; lb = kb - 1563; }
    else if (kb < 3127) { r = 2; lb = kb - 2345; }
    else                { r = 3; lb = kb - 3127; }
    const int stt[4] = {2, 0, 0, 1};
    const int st = stt[r];
    const int cnt[3] = {NQn, NAn, NKn};
    const long noff[3] = {0, NQn, NQn + NAn};
    const int n0 = lb * 128;
    const int n = cnt[st];
    const long rb = c_rbase[r];
    const int tid = threadIdx.x;

    stage_w<128, 64>(ldsW, wtb + WFT_U + r * 8192, tid);
    stage_bf16<64>(ldsX, xsb + noff[st] * 64, n0, n, tid);
    __syncthreads();

    const int w = tid >> 6, lane = tid & 63;
    f32x4 acc[2][8] = {};
    mfma_core<64, 8>(ldsX, ldsW, acc, lane, w);

    const int prow = (lane >> 4) * 4, pcol = lane & 15;
    #pragma unroll
    for (int mf = 0; mf < 2; ++mf)
      #pragma unroll
      for (int nf = 0; nf < 8; ++nf)
        #pragma unroll
        for (int i = 0; i < 4; ++i) {
            int node = n0 + w * 32 + mf * 16 + prow + i;
            if (node < n) {
                int col = nf * 16 + pcol;
                kvb[(rb + node) * 128 + col] = f2bf(acc[mf][nf][i] + wfb[r * 128 + col]);
            }
        }
}

// ---- head: z = beta*(gelu(out) @ a_w + a_b) + (1-beta)*xs ----
__global__ void __launch_bounds__(256)
head_mfma(const float* __restrict__ outa, const unsigned short* __restrict__ xsb,
          const unsigned short* __restrict__ wtb, const float* __restrict__ a_b,
          const float* __restrict__ skip, float* __restrict__ z)
{
    __shared__ unsigned short ldsX[128 * 64];
    __shared__ unsigned short ldsW[64 * 64];
    int t, n0; type_of_block128(blockIdx.x, t, n0);
    const int cnt[3] = {NQn, NAn, NKn};
    const long noff[3] = {0, NQn, NQn + NAn};
    const long zoff[3] = {200000L, 6600000L, 19400000L};
    const int n = cnt[t];
    const int tid = threadIdx.x;

    stage_w<64, 64>(ldsW, wtb + AT_U + t * 4096, tid);
    stage_f32<64, true>(ldsX, outa + noff[t] * 64, n0, n, tid);
    __syncthreads();

    const int w = tid >> 6, lane = tid & 63;
    f32x4 acc[2][4] = {};
    mfma_core<64, 4>(ldsX, ldsW, acc, lane, w);

    const float beta = 1.f / (1.f + expf(-skip[t]));
    const int prow = (lane >> 4) * 4, pcol = lane & 15;
    #pragma unroll
    for (int mf = 0; mf < 2; ++mf)
      #pragma unroll
      for (int nf = 0; nf < 4; ++nf)
        #pragma unroll
        for (int i = 0; i < 4; ++i) {
            int node = n0 + w * 32 + mf * 16 + prow + i;
            if (node < n) {
                int col = nf * 16 + pcol;
                float o = acc[mf][nf][i] + a_b[t * 64 + col];
                float rv = bf2f(xsb[(noff[t] + node) * 64 + col]);
                z[zoff[t] + (long)node * 64 + col] = beta * o + (1.f - beta) * rv;
            }
        }
}

// ---- CSR build, all 4 relations at once ------------------------------------
__global__ void csr_count_all(const int* __restrict__ d0, const int* __restrict__ d1,
                              const int* __restrict__ d2, const int* __restrict__ d3,
                              int* __restrict__ deg)
{
    int gid = blockIdx.x * 256 + threadIdx.x;
    if (gid < 800000)       atomicAdd(&deg[d0[gid]], 1);
    else if (gid < 1600000) atomicAdd(&deg[100000 + d1[gid - 800000]], 1);
    else if (gid < 2000000) atomicAdd(&deg[300000 + d2[gid - 1600000]], 1);
    else if (gid < 2400000) atomicAdd(&deg[500000 + d3[gid - 2000000]], 1);
}

__global__ void csr_fill_all(const int* __restrict__ s0, const int* __restrict__ d0,
                             const int* __restrict__ s1, const int* __restrict__ d1,
                             const int* __restrict__ s2, const int* __restrict__ d2,
                             const int* __restrict__ s3, const int* __restrict__ d3,
                             const int* __restrict__ off, int* __restrict__ cur,
                             int* __restrict__ csrc)
{
    int gid = blockIdx.x * 256 + threadIdx.x;
    int seg, s;
    if (gid < 800000)       { seg = d0[gid];                    s = s0[gid]; }
    else if (gid < 1600000) { seg = 100000 + d1[gid - 800000];  s = s1[gid - 800000]; }
    else if (gid < 2000000) { seg = 300000 + d2[gid - 1600000]; s = s2[gid - 1600000]; }
    else if (gid < 2400000) { seg = 500000 + d3[gid - 2000000]; s = s3[gid - 2000000]; }
    else return;
    int slot = off[seg] + atomicAdd(&cur[seg], 1);
    csrc[slot] = s;
}

__global__ void scan1(const int* __restrict__ in, int* __restrict__ out,
                      int* __restrict__ part, int n)
{
    __shared__ int lds[256];
    const int tid = threadIdx.x;
    const int base = blockIdx.x * 1024 + tid * 4;
    int v[4];
    #pragma unroll
    for (int k = 0; k < 4; ++k) v[k] = (base + k < n) ? in[base + k] : 0;
    int tsum = v[0] + v[1] + v[2] + v[3];
    lds[tid] = tsum;
    __syncthreads();
    for (int off = 1; off < 256; off <<= 1) {
        int t = (tid >= off) ? lds[tid - off] : 0;
        __syncthreads();
        lds[tid] += t;
        __syncthreads();
    }
    int excl = lds[tid] - tsum;
    #pragma unroll
    for (int k = 0; k < 4; ++k) {
        if (base + k < n) out[base + k] = excl;
        excl += v[k];
    }
    if (tid == 255) part[blockIdx.x] = lds[255];
}

__global__ void scan2(int* __restrict__ part, int nb)   // nb <= 1024
{
    __shared__ int lds[256];
    const int tid = threadIdx.x;
    const int base = tid * 4;
    int v[4];
    #pragma unroll
    for (int k = 0; k < 4; ++k) v[k] = (base + k < nb) ? part[base + k] : 0;
    int tsum = v[0] + v[1] + v[2] + v[3];
    lds[tid] = tsum;
    __syncthreads();
    for (int off = 1; off < 256; off <<= 1) {
        int t = (tid >= off) ? lds[tid - off] : 0;
        __syncthreads();
        lds[tid] += t;
        __syncthreads();
    }
    int excl = lds[tid] - tsum;
    #pragma unroll
    for (int k = 0; k < 4; ++k) {
        if (base + k < nb) part[base + k] = excl;
        excl += v[k];
    }
}

__global__ void scan3(int* __restrict__ off, const int* __restrict__ part, int n, int E)
{
    int i = blockIdx.x * 256 + threadIdx.x;
    if (i < n) off[i] += part[i >> 10];
    if (i == 0) off[n] = E;
}

// ---- merged fused attention ------------------------------------------------
__device__ inline float attn_seg(const int* __restrict__ csrc, int begin, int end,
                                 const unsigned short* __restrict__ kv, long kvbase,
                                 float qv, float pscale, int lane)
{
    float m = -INFINITY, ssum = 0.f, acc = 0.f;
    for (int t = begin; t < end; t += 4) {
        int i1 = t + 1 < end ? t + 1 : end - 1;
        int i2 = t + 2 < end ? t + 2 : end - 1;
        int i3 = t + 3 < end ? t + 3 : end - 1;
        int s0 = csrc[t], s1 = csrc[i1], s2 = csrc[i2], s3 = csrc[i3];
        ushort2 c0 = ((const ushort2*)(kv + (kvbase + s0) * 128))[lane];
        ushort2 c1 = ((const ushort2*)(kv + (kvbase + s1) * 128))[lane];
        ushort2 c2 = ((const ushort2*)(kv + (kvbase + s2) * 128))[lane];
        ushort2 c3 = ((const ushort2*)(kv + (kvbase + s3) * 128))[lane];
        float p0 = qv * bf2f(c0.x), p1 = qv * bf2f(c1.x);
        float p2 = qv * bf2f(c2.x), p3 = qv * bf2f(c3.x);
        p0 += __shfl_xor(p0, 1);  p1 += __shfl_xor(p1, 1);
        p2 += __shfl_xor(p2, 1);  p3 += __shfl_xor(p3, 1);
        p0 += __shfl_xor(p0, 2);  p1 += __shfl_xor(p1, 2);
        p2 += __shfl_xor(p2, 2);  p3 += __shfl_xor(p3, 2);
        p0 += __shfl_xor(p0, 4);  p1 += __shfl_xor(p1, 4);
        p2 += __shfl_xor(p2, 4);  p3 += __shfl_xor(p3, 4);
        p0 += __shfl_xor(p0, 8);  p1 += __shfl_xor(p1, 8);
        p2 += __shfl_xor(p2, 8);  p3 += __shfl_xor(p3, 8);
        p0 += __shfl_xor(p0, 16); p1 += __shfl_xor(p1, 16);
        p2 += __shfl_xor(p2, 16); p3 += __shfl_xor(p3, 16);
        float a0 = p0 * pscale;
        float a1 = (t + 1 < end) ? p1 * pscale : -INFINITY;
        float a2 = (t + 2 < end) ? p2 * pscale : -INFINITY;
        float a3 = (t + 3 < end) ? p3 * pscale : -INFINITY;
        float tm = fmaxf(fmaxf(a0, a1), fmaxf(a2, a3));
        float mn = fmaxf(m, tm);
        float corr = __expf(m - mn);
        float w0 = __expf(a0 - mn), w1 = __expf(a1 - mn);
        float w2 = __expf(a2 - mn), w3 = __expf(a3 - mn);
        ssum = ssum * corr + ((w0 + w1) + (w2 + w3));
        acc = acc * corr + (w0 * bf2f(c0.y) + w1 * bf2f(c1.y))
                         + (w2 * bf2f(c2.y) + w3 * bf2f(c3.y));
        m = mn;
    }
    return acc / (ssum + 1e-16f);
}

__global__ void __launch_bounds__(256)
attn_all(const int* __restrict__ off, const int* __restrict__ csrc,
         const unsigned short* __restrict__ qbf, const unsigned short* __restrict__ kv,
         const float* __restrict__ prel, float scale, float* __restrict__ out)
{
    const int wid = blockIdx.x * 4 + (threadIdx.x >> 6);
    const int lane = threadIdx.x & 63;
    if (wid >= 500000) return;
    const int h = lane >> 5;

    if (wid < 100000) {
        const long row = wid;
        const float qv = bf2f(qbf[row * 64 + lane]);
        float r0 = attn_seg(csrc, off[wid], off[wid + 1], kv, c_rbase[0],
                            qv, prel[0 * 2 + h] * scale, lane);
        float r3 = attn_seg(csrc, off[500000 + wid], off[500000 + wid + 1], kv, c_rbase[3],
                            qv, prel[3 * 2 + h] * scale, lane);
        out[row * 64 + lane] = r0 + r3;
    } else if (wid < 300000) {
        const int kk = wid - 100000;
        const long row = 300000 + kk;
        const float qv = bf2f(qbf[row * 64 + lane]);
        float r1 = attn_seg(csrc, off[100000 + kk], off[100000 + kk + 1], kv, c_rbase[1],
                            qv, prel[1 * 2 + h] * scale, lane);
        out[row * 64 + lane] = r1;
    } else {
        const int aa = wid - 300000;
        const long row = 100000 + aa;
        const float qv = bf2f(qbf[row * 64 + lane]);
        float r2 = attn_seg(csrc, off[300000 + aa], off[300000 + aa + 1], kv, c_rbase[2],
                            qv, prel[2 * 2 + h] * scale, lane);
        out[row * 64 + lane] = r2;
    }
}

// ---- link prediction --------------------------------------------------------
__global__ void pred_all(const int* __restrict__ psrc, const int* __restrict__ pdst,
                         const int* __restrict__ nsrc, const int* __restrict__ ndst,
                         const float* __restrict__ zq, const float* __restrict__ za,
                         float* __restrict__ out)
{
    int t = blockIdx.x * 256 + threadIdx.x;
    int g = t >> 3, lane = t & 7;
    if (g >= EPc + ENc) return;
    int s, d;
    if (g < EPc) { s = psrc[g]; d = pdst[g]; }
    else         { int gg = g - EPc; s = nsrc[gg]; d = ndst[gg]; }
    const float4* zs = (const float4*)&zq[(long)s * 64 + lane * 8];
    const float4* zd = (const float4*)&za[(long)d * 64 + lane * 8];
    float4 a0 = zs[0], a1 = zs[1], b0 = zd[0], b1 = zd[1];
    float p = a0.x * b0.x + a0.y * b0.y + a0.z * b0.z + a0.w * b0.w
            + a1.x * b1.x + a1.y * b1.y + a1.z * b1.z + a1.w * b1.w;
    p += __shfl_xor(p, 1);
    p += __shfl_xor(p, 2);
    p += __shfl_xor(p, 4);
    if (lane == 0) out[g] = 1.f / (1.f + expf(-p));
}

} // namespace

extern "C" void kernel_launch(void* const* d_in, const int* in_sizes, int n_in,
                              void* d_out, int out_size, void* d_ws, size_t ws_size,
                              hipStream_t stream)
{
    const float* xq    = (const float*)d_in[0];
    const float* xa    = (const float*)d_in[1];
    const float* xk    = (const float*)d_in[2];
    const float* lin_w = (const float*)d_in[3];
    const float* lin_b = (const float*)d_in[4];
    const float* k_w   = (const float*)d_in[5];
    const float* k_b   = (const float*)d_in[6];
    const float* q_w   = (const float*)d_in[7];
    const float* q_b   = (const float*)d_in[8];
    const float* v_w   = (const float*)d_in[9];
    const float* v_b   = (const float*)d_in[10];
    const float* a_w   = (const float*)d_in[11];
    const float* a_b   = (const float*)d_in[12];
    const float* a_rel = (const float*)d_in[13];
    const float* m_rel = (const float*)d_in[14];
    const float* p_rel = (const float*)d_in[15];
    const float* skip  = (const float*)d_in[16];
    const int* esrc[4] = {(const int*)d_in[17], (const int*)d_in[19], (const int*)d_in[21], (const int*)d_in[23]};
    const int* edst[4] = {(const int*)d_in[18], (const int*)d_in[20], (const int*)d_in[22], (const int*)d_in[24]};
    const int* pos_src = (const int*)d_in[25];
    const int* pos_dst = (const int*)d_in[26];
    const int* neg_src = (const int*)d_in[27];
    const int* neg_dst = (const int*)d_in[28];

    float* ws   = (float*)d_ws;
    float* outp = (float*)d_out;
    int*   wi   = (int*)(ws + INT_OFF);
    unsigned short* xsb = (unsigned short*)(ws + XSB_OFF);
    unsigned short* qbf = (unsigned short*)(ws + QBF_OFF);
    unsigned short* kvb = (unsigned short*)(ws + KV_OFF);
    unsigned short* wtb = (unsigned short*)(ws + WTB_OFF);
    float*          wfb = ws + WFB_OFF;

    // CSR build (once, all relations)
    hipMemsetAsync(wi + DEG_I, 0, 1200000L * sizeof(int), stream);
    csr_count_all<<<(ETOT + 255) / 256, 256, 0, stream>>>(
        edst[0], edst[1], edst[2], edst[3], wi + DEG_I);
    const int nb = (NSEG + 1023) / 1024;   // 586
    scan1<<<nb, 256, 0, stream>>>(wi + DEG_I, wi + OFFS_I, wi + PART_I, NSEG);
    scan2<<<1, 256, 0, stream>>>(wi + PART_I, nb);
    scan3<<<(NSEG + 255) / 256, 256, 0, stream>>>(wi + OFFS_I, wi + PART_I, NSEG, ETOT);
    csr_fill_all<<<(ETOT + 255) / 256, 256, 0, stream>>>(
        esrc[0], edst[0], esrc[1], edst[1], esrc[2], edst[2], esrc[3], edst[3],
        wi + OFFS_I, wi + CUR_I, wi + CSRC_I);

    // weight prep
    fuse_weights<<<4, 256, 0, stream>>>(k_w, k_b, v_w, v_b, a_rel, m_rel, wtb, wfb);
    prep_w<<<192, 256, 0, stream>>>(lin_w, q_w, a_w, wtb);

    // node GEMMs (MFMA)
    lin_mfma<<<3908, 256, 0, stream>>>(xq, xa, xk, wtb, lin_b, xsb);
    q_mfma<<<3908, 256, 0, stream>>>(xsb, wtb, q_b, qbf);
    kv_mfma<<<4690, 256, 0, stream>>>(xsb, wtb, wfb, kvb);

    // merged attention over all 500k destination nodes
    const float scale = 0.17677669529663687f;   // 1/sqrt(32)
    attn_all<<<125000, 256, 0, stream>>>(wi + OFFS_I, wi + CSRC_I, qbf, kvb,
                                         p_rel, scale, ws + OUT_OFF);

    // output head
    head_mfma<<<3908, 256, 0, stream>>>(ws + OUT_OFF, xsb, wtb, a_b, skip, outp);

    // link predictions
    pred_all<<<(200000 * 8 + 255) / 256, 256, 0, stream>>>(
        pos_src, pos_dst, neg_src, neg_dst,
        outp + 200000, outp + 6600000, outp);
}